// Round 1
// baseline (450.736 us; speedup 1.0000x reference)
//
#include <hip/hip_runtime.h>
#include <stdint.h>

typedef unsigned short u16;
typedef __attribute__((ext_vector_type(8))) short short8;
typedef __attribute__((ext_vector_type(4))) short short4v;
typedef __attribute__((ext_vector_type(4))) float float4v;

union V8u { short8 v; short4v h[2]; u16 u[8]; unsigned w[4]; };

__device__ __forceinline__ u16 f2bf(float f) {
  unsigned u = __float_as_uint(f);
  u = u + 0x7FFFu + ((u >> 16) & 1u);   // round-to-nearest-even
  return (u16)(u >> 16);
}
__device__ __forceinline__ float4v fzero() {
  float4v z = {0.f, 0.f, 0.f, 0.f};
  return z;
}
__device__ __forceinline__ void gl_lds16(const u16* g, u16* l) {
  __builtin_amdgcn_global_load_lds(
      (const __attribute__((address_space(1))) void*)g,
      (__attribute__((address_space(3))) void*)l, 16, 0, 0);
}

#define MFMA16(a, b, c) __builtin_amdgcn_mfma_f32_16x16x32_bf16((a), (b), (c), 0, 0, 0)

// ---------------------------------------------------------------------------
// fp32 -> bf16 for 5 contiguous segments: X (2 segs) + wq,wk,wv. 8 elems/thr.
// ---------------------------------------------------------------------------
__global__ void conv5_f32_bf16(const float* __restrict__ X,
                               const float* __restrict__ w0,
                               const float* __restrict__ w1,
                               const float* __restrict__ w2,
                               u16* __restrict__ dst, long seg) {
  const int y = blockIdx.y;
  const float* s = (y < 2) ? (X + (long)y * seg)
                           : (y == 2 ? w0 : (y == 3 ? w1 : w2));
  u16* d = dst + (long)y * seg;
  const long i = ((long)blockIdx.x * 256 + threadIdx.x) * 8;
  if (i >= seg) return;
  float4 a = *(const float4*)&s[i];
  float4 b = *(const float4*)&s[i + 4];
  V8u o;
  o.u[0] = f2bf(a.x); o.u[1] = f2bf(a.y); o.u[2] = f2bf(a.z); o.u[3] = f2bf(a.w);
  o.u[4] = f2bf(b.x); o.u[5] = f2bf(b.y); o.u[6] = f2bf(b.z); o.u[7] = f2bf(b.w);
  *(short8*)&d[i] = o.v;
}

__global__ void conv_f32_bf16(const float* __restrict__ in, u16* __restrict__ out, long n) {
  const long i = ((long)blockIdx.x * 256 + threadIdx.x) * 8;
  if (i >= n) return;
  float4 a = *(const float4*)&in[i];
  float4 b = *(const float4*)&in[i + 4];
  V8u o;
  o.u[0] = f2bf(a.x); o.u[1] = f2bf(a.y); o.u[2] = f2bf(a.z); o.u[3] = f2bf(a.w);
  o.u[4] = f2bf(b.x); o.u[5] = f2bf(b.y); o.u[6] = f2bf(b.z); o.u[7] = f2bf(b.w);
  *(short8*)&out[i] = o.v;
}

// ---------------------------------------------------------------------------
// Fused QKV GEMM, 256x256 tile, 8 waves, ring-4 32-K chunk pipeline.
//   O[m][n] = sum_k X[m][k]*Wb[n][k] + bias[n],  N = 6144 (Wq|Wk|Wv rows).
// T2: XOR-swizzled LDS (byte ^= (byte>>3)&0x30, involution; even 8-lane slots)
// T3/T4: counted s_waitcnt vmcnt(8) + raw s_barrier; 2 chunks always in
//        flight, never drained in the main loop (tail symmetric via clamped
//        dummy stages into dead ring slots).
// T5: s_setprio(1) around the 32-MFMA cluster.
// Race-freedom: slot (c+3)&3 == slot of chunk c-1, whose ds_reads completed
// before the end-of-phase-(c-1) barrier; stage issue happens after it.
// ---------------------------------------------------------------------------
__global__ __launch_bounds__(512, 2) void gemm256_qkv(
    const u16* __restrict__ X, const u16* __restrict__ Wb,
    const float* __restrict__ bq, const float* __restrict__ bk,
    const float* __restrict__ bv, u16* __restrict__ Out, int K)
{
  __shared__ u16 AB[4][2][8192];   // [slot][A/B][256 rows * 32 k] = 128 KiB

  const int t = threadIdx.x;            // 0..511
  const int lane = t & 63;
  const int wave = t >> 6;              // 0..7
  const int quad = lane >> 4, l16 = lane & 15;
  const int wm = wave >> 2, wn = wave & 3;  // 2 x 4 wave grid

  const long m0 = (long)blockIdx.y * 256;
  const long n0 = (long)blockIdx.x * 256;

  // --- staging precompute: per-thread 4 loads/phase (A x2, B x2) ------------
  // linear LDS dest byte o = l*8192 + t*16 ; global source = inverse-swizzle
  int arow[2], acol[2];
  #pragma unroll
  for (int l = 0; l < 2; ++l) {
    const int o = l * 8192 + t * 16;
    const int lg = o ^ ((o >> 3) & 0x30);   // involution
    arow[l] = lg >> 6;                       // row in 256-row tile
    acol[l] = (lg & 63) >> 1;                // k-elem offset in 32-k chunk
  }
  const u16* bAs[2]; const u16* bBs[2];
  #pragma unroll
  for (int l = 0; l < 2; ++l) {
    bAs[l] = X  + (m0 + arow[l]) * K + acol[l];
    bBs[l] = Wb + (n0 + arow[l]) * K + acol[l];
  }
  const int dA0 = t * 8, dA1 = 4096 + t * 8;   // u16 dest offsets (linear)

  // --- ds_read offsets (swizzled) per fragment ------------------------------
  int offA[8], offB[4];
  #pragma unroll
  for (int i = 0; i < 8; ++i) {
    const int r = wm * 128 + i * 16 + l16;
    const int lg = r * 64 + quad * 16;
    offA[i] = (lg ^ ((lg >> 3) & 0x30)) >> 1;
  }
  #pragma unroll
  for (int n = 0; n < 4; ++n) {
    const int r = wn * 64 + n * 16 + l16;
    const int lg = r * 64 + quad * 16;
    offB[n] = (lg ^ ((lg >> 3) & 0x30)) >> 1;
  }

  float4v acc[8][4];
  #pragma unroll
  for (int i = 0; i < 8; ++i)
    #pragma unroll
    for (int n = 0; n < 4; ++n) acc[i][n] = fzero();

  // --- prologue: chunks 0,1,2 -> slots 0,1,2 (12 loads in flight) -----------
  #pragma unroll
  for (int c = 0; c < 3; ++c) {
    u16* Ad = &AB[c][0][0];
    u16* Bd = &AB[c][1][0];
    gl_lds16(bAs[0] + c * 32, Ad + dA0);
    gl_lds16(bBs[0] + c * 32, Bd + dA0);
    gl_lds16(bAs[1] + c * 32, Ad + dA1);
    gl_lds16(bBs[1] + c * 32, Bd + dA1);
  }
  asm volatile("s_waitcnt vmcnt(8)\n\ts_barrier" ::: "memory");  // chunk 0 resident

  const int NCH = K >> 5;   // 64 chunks
  for (int c = 0; c < NCH; ++c) {
    const u16* Ac = &AB[c & 3][0][0];
    const u16* Bc = &AB[c & 3][1][0];

    short8 b[4], a[8];
    #pragma unroll
    for (int n = 0; n < 4; ++n) b[n] = *(const short8*)&Bc[offB[n]];
    #pragma unroll
    for (int i = 0; i < 8; ++i) a[i] = *(const short8*)&Ac[offA[i]];

    // stage chunk c+3 (clamped dummy in tail keeps vmcnt accounting symmetric;
    // dead slot (c+3)&3 is never read once c+3 >= NCH)
    int cs = c + 3; if (cs >= NCH) cs = NCH - 1;
    u16* Ad = &AB[(c + 3) & 3][0][0];
    u16* Bd = &AB[(c + 3) & 3][1][0];
    gl_lds16(bAs[0] + cs * 32, Ad + dA0);
    gl_lds16(bBs[0] + cs * 32, Bd + dA0);
    gl_lds16(bAs[1] + cs * 32, Ad + dA1);
    gl_lds16(bBs[1] + cs * 32, Bd + dA1);
    __builtin_amdgcn_sched_barrier(0);   // pin stage-issue before MFMA block

    __builtin_amdgcn_s_setprio(1);
    #pragma unroll
    for (int i = 0; i < 8; ++i)
      #pragma unroll
      for (int n = 0; n < 4; ++n)
        acc[i][n] = MFMA16(a[i], b[n], acc[i][n]);
    __builtin_amdgcn_s_setprio(0);

    // chunk c+1 (issued 2 phases ago; newest 8 loads = chunks c+2,c+3) landed
    asm volatile("s_waitcnt vmcnt(8)\n\ts_barrier" ::: "memory");
  }

  // --- epilogue: bias + bf16 store, Q/K/V selected by fused column ----------
  #pragma unroll
  for (int n = 0; n < 4; ++n) {
    const int cg = (int)n0 + wn * 64 + n * 16 + l16;     // 0..6143
    const int z = cg >> 11, col = cg & 2047;
    const float* Bp = (z == 0) ? bq : (z == 1 ? bk : bv);
    const float bvv = Bp[col];
    u16* Op = Out + (long)z * (4096L * 2048);
    #pragma unroll
    for (int i = 0; i < 8; ++i) {
      const long r0 = m0 + wm * 128 + i * 16 + quad * 4;
      #pragma unroll
      for (int r = 0; r < 4; ++r)
        Op[(r0 + r) * 2048 + col] = f2bf(acc[i][n][r] + bvv);
    }
  }
}

// ---------------------------------------------------------------------------
// GEMM: O[m][n] = sum_k X[m][k]*W[n][k] + bias[n].  bf16 ops, fp32 acc/bias.
// m97 structure. Kept for the output projection (512 balanced blocks).
// ---------------------------------------------------------------------------
template <bool OUTF32>
__global__ __launch_bounds__(256, 2) void gemm_bt_bias(
    const u16* __restrict__ X,
    const u16* __restrict__ W0, const float* __restrict__ B0, void* __restrict__ O0,
    const u16* __restrict__ W1, const float* __restrict__ B1, void* __restrict__ O1,
    const u16* __restrict__ W2, const float* __restrict__ B2, void* __restrict__ O2,
    int M, int N, int K)
{
  const u16* W = W0; const float* Bb = B0; void* Ov = O0;
  if (blockIdx.z == 1) { W = W1; Bb = B1; Ov = O1; }
  else if (blockIdx.z == 2) { W = W2; Bb = B2; Ov = O2; }

  __shared__ u16 As[128 * 32];
  __shared__ u16 Bs[128 * 32];

  const int t = threadIdx.x;
  const int lane = t & 63, wave = t >> 6;
  const int quad = lane >> 4, l16 = lane & 15;
  const int wm = wave >> 1, wn = wave & 1;
  const long m0 = (long)blockIdx.y * 128;
  const long n0 = (long)blockIdx.x * 128;

  const int srow = t >> 2;
  const int scol = (t & 3) * 8;

  float4v acc[4][4];
  #pragma unroll
  for (int i = 0; i < 4; ++i)
    #pragma unroll
    for (int j = 0; j < 4; ++j) acc[i][j] = fzero();

  for (int k0 = 0; k0 < K; k0 += 32) {
    gl_lds16(&X[(m0 + srow) * K + k0 + scol],      &As[t * 8]);
    gl_lds16(&X[(m0 + srow + 64) * K + k0 + scol], &As[t * 8 + 64 * 32]);
    gl_lds16(&W[(n0 + srow) * K + k0 + scol],      &Bs[t * 8]);
    gl_lds16(&W[(n0 + srow + 64) * K + k0 + scol], &Bs[t * 8 + 64 * 32]);
    __syncthreads();

    short8 a[4], b[4];
    #pragma unroll
    for (int mi = 0; mi < 4; ++mi)
      a[mi] = *(const short8*)&As[(wm * 64 + mi * 16 + l16) * 32 + quad * 8];
    #pragma unroll
    for (int ni = 0; ni < 4; ++ni)
      b[ni] = *(const short8*)&Bs[(wn * 64 + ni * 16 + l16) * 32 + quad * 8];
    #pragma unroll
    for (int mi = 0; mi < 4; ++mi)
      #pragma unroll
      for (int ni = 0; ni < 4; ++ni)
        acc[mi][ni] = MFMA16(a[mi], b[ni], acc[mi][ni]);
    __syncthreads();
  }

  #pragma unroll
  for (int ni = 0; ni < 4; ++ni) {
    const long cg = n0 + wn * 64 + ni * 16 + l16;
    const float bv = Bb[cg];
    #pragma unroll
    for (int mi = 0; mi < 4; ++mi) {
      const long rg0 = m0 + wm * 64 + mi * 16 + quad * 4;
      #pragma unroll
      for (int r = 0; r < 4; ++r) {
        const float v = acc[mi][ni][r] + bv;
        if (OUTF32) ((float*)Ov)[(rg0 + r) * N + cg] = v;
        else        ((u16*)Ov)[(rg0 + r) * N + cg] = f2bf(v);
      }
    }
  }
}

// ---------------------------------------------------------------------------
// Causal flash attention, fixed-scale softmax + ones-column row-sum,
// 32 Q rows per wave / 128 Q rows per block. (unchanged this round)
// ---------------------------------------------------------------------------
#define S_LEN 2048
#define HID   2048
#define HD    128

__global__ __launch_bounds__(256, 2) void attn_fwd(
    const u16* __restrict__ Q, const u16* __restrict__ K,
    const u16* __restrict__ V, u16* __restrict__ Ctx)
{
  __shared__ u16 Ks[2][32 * 136];      // K rows natural, pad 8
  __shared__ unsigned Vt[2][128 * 17]; // Vt[c][r/2] = V[2r'][c] | V[2r'+1][c]<<16
  __shared__ u16 Ps[4 * 2 * 512];      // per-wave, per-group P round-trip

  const int t = threadIdx.x;
  const int lane = t & 63, wave = t >> 6;
  const int quad = lane >> 4, l16 = lane & 15;
  const int qb = (int)(gridDim.x - 1 - blockIdx.x) * 128;  // heavy blocks first
  const int b = blockIdx.y >> 4, h = blockIdx.y & 15;

  const long base = (long)b * S_LEN * HID + (long)h * HD;
  const u16* Qp = Q + base;
  const u16* Kp = K + base;
  const u16* Vp = V + base;

  const int sr2 = t >> 4;          // 0..15: rows 2*sr2, 2*sr2+1 of the tile
  const int sc8 = (t & 15) * 8;    // feature col base
  const int wqb = qb + wave * 32;  // wave's first Q row

  // Q fragments for both groups (A-layout: m=lane&15, k=quad*8+j)
  short8 qf[2][4];
  #pragma unroll
  for (int g = 0; g < 2; ++g) {
    const long qr = wqb + g * 16 + l16;
    #pragma unroll
    for (int kk = 0; kk < 4; ++kk)
      qf[g][kk] = *(const short8*)&Qp[qr * HID + kk * 32 + quad * 8];
  }

  short8 onesv;
  {
    V8u ou;
    #pragma unroll
    for (int j = 0; j < 8; ++j) ou.u[j] = 0x3F80;   // bf16 1.0
    onesv = ou.v;
  }

  float4v o[2][9];                 // per group: [0..7] d-groups, [8] row-sum
  #pragma unroll
  for (int g = 0; g < 2; ++g)
    #pragma unroll
    for (int i = 0; i < 9; ++i) o[g][i] = fzero();
  const float SC = 0.08838834764831845f * 1.4426950408889634f; // scale*log2e

  // prefetch tile 0 into regs, commit to buf 0
  short8 kr0, kr1, vv0, vv1;
  {
    const long g = (long)(2 * sr2) * HID + sc8;
    kr0 = *(const short8*)&Kp[g];
    kr1 = *(const short8*)&Kp[g + HID];
    vv0 = *(const short8*)&Vp[g];
    vv1 = *(const short8*)&Vp[g + HID];
  }
  {
    *(short8*)&Ks[0][(2 * sr2) * 136 + sc8]     = kr0;
    *(short8*)&Ks[0][(2 * sr2 + 1) * 136 + sc8] = kr1;
    V8u a, c; a.v = vv0; c.v = vv1;
    #pragma unroll
    for (int j = 0; j < 8; ++j)
      Vt[0][(sc8 + j) * 17 + sr2] = (unsigned)a.u[j] | ((unsigned)c.u[j] << 16);
  }
  __syncthreads();

  const int T = (qb + 128) >> 5;   // number of 32-row KV tiles
  for (int ti = 0; ti < T; ++ti) {
    const int kv0 = ti << 5;
    const int p = ti & 1;

    const bool more = (ti + 1 < T);
    if (more) {
      const long g = (long)(kv0 + 32 + 2 * sr2) * HID + sc8;
      kr0 = *(const short8*)&Kp[g];
      kr1 = *(const short8*)&Kp[g + HID];
      vv0 = *(const short8*)&Vp[g];
      vv1 = *(const short8*)&Vp[g + HID];
    }

    // wave-uniform activity: both groups share it (kv0, wqb both 32-aligned)
    if (kv0 <= wqb) {
      // ---- S = Q . K^T for both groups (kf read once, used twice) ----
      float4v s[2][2];
      #pragma unroll
      for (int g = 0; g < 2; ++g) { s[g][0] = fzero(); s[g][1] = fzero(); }
      #pragma unroll
      for (int ni = 0; ni < 2; ++ni)
        #pragma unroll
        for (int kk = 0; kk < 4; ++kk) {
          short8 kf = *(const short8*)&Ks[p][(ni * 16 + l16) * 136 + kk * 32 + quad * 8];
          s[0][ni] = MFMA16(qf[0][kk], kf, s[0][ni]);
          s[1][ni] = MFMA16(qf[1][kk], kf, s[1][ni]);
        }

      // ---- fixed-scale exp + causal mask + P round-trip per group ----
      const int pb = wave * 1024;
      #pragma unroll
      for (int g = 0; g < 2; ++g) {
        const int qrow0 = wqb + g * 16 + quad * 4;
        #pragma unroll
        for (int r = 0; r < 4; ++r) {
          float s0 = fminf(s[g][0][r] * SC, 80.f);
          float s1 = fminf(s[g][1][r] * SC, 80.f);
          if (kv0 + l16 > qrow0 + r)      s0 = -1e30f;
          if (kv0 + 16 + l16 > qrow0 + r) s1 = -1e30f;
          Ps[pb + g * 512 + (quad * 4 + r) * 32 + l16]      = f2bf(__builtin_amdgcn_exp2f(s0));
          Ps[pb + g * 512 + (quad * 4 + r) * 32 + 16 + l16] = f2bf(__builtin_amdgcn_exp2f(s1));
        }
      }
      __threadfence_block();
      short8 pf0 = *(const short8*)&Ps[pb + l16 * 32 + quad * 8];
      short8 pf1 = *(const short8*)&Ps[pb + 512 + l16 * 32 + quad * 8];

      // ---- O += P . V (vf read once, used twice) ; ones row-sum ----
      #pragma unroll
      for (int dt = 0; dt < 8; ++dt) {
        const unsigned* vp = &Vt[p][(dt * 16 + l16) * 17 + quad * 4];
        V8u vf;
        vf.w[0] = vp[0]; vf.w[1] = vp[1]; vf.w[2] = vp[2]; vf.w[3] = vp[3];
        o[0][dt] = MFMA16(pf0, vf.v, o[0][dt]);
        o[1][dt] = MFMA16(pf1, vf.v, o[1][dt]);
      }
      o[0][8] = MFMA16(pf0, onesv, o[0][8]);
      o[1][8] = MFMA16(pf1, onesv, o[1][8]);
    }

    if (more) {
      *(short8*)&Ks[1 - p][(2 * sr2) * 136 + sc8]     = kr0;
      *(short8*)&Ks[1 - p][(2 * sr2 + 1) * 136 + sc8] = kr1;
      V8u a, c; a.v = vv0; c.v = vv1;
      #pragma unroll
      for (int j = 0; j < 8; ++j)
        Vt[1 - p][(sc8 + j) * 17 + sr2] = (unsigned)a.u[j] | ((unsigned)c.u[j] << 16);
    }
    __syncthreads();
  }

  // ---- epilogue: O / L -> ctx (merged-head layout [B*S][H]) ----
  u16* Cp = Ctx + base;
  #pragma unroll
  for (int g = 0; g < 2; ++g)
    #pragma unroll
    for (int r = 0; r < 4; ++r) {
      const float inv = 1.0f / o[g][8][r];
      const long qr = wqb + g * 16 + quad * 4 + r;
      #pragma unroll
      for (int dt = 0; dt < 8; ++dt)
        Cp[qr * HID + dt * 16 + l16] = f2bf(o[g][dt][r] * inv);
    }
}

// ---------------------------------------------------------------------------
extern "C" void kernel_launch(void* const* d_in, const int* in_sizes, int n_in,
                              void* d_out, int out_size, void* d_ws, size_t ws_size,
                              hipStream_t stream) {
  const float* X  = (const float*)d_in[0];
  const float* wq = (const float*)d_in[1];
  const float* bq = (const float*)d_in[2];
  const float* wk = (const float*)d_in[3];
  const float* bk = (const float*)d_in[4];
  const float* wv = (const float*)d_in[5];
  const float* bv = (const float*)d_in[6];
  const float* wo = (const float*)d_in[7];
  const float* bo = (const float*)d_in[8];
  float* out = (float*)d_out;

  const long HSZ = 4096L * 2048;   // B*S x H
  const long WSZ = 2048L * 2048;
  // ws (bf16 elems): Qw Kw Vw (3x16.8MB) + Xb (16.8MB) + W0..W2 (3x8.4MB)
  u16* Qw = (u16*)d_ws;
  u16* Kw = Qw + HSZ;
  u16* Vw = Kw + HSZ;
  u16* Xb = Vw + HSZ;
  u16* Wb = Xb + HSZ;              // W0,W1,W2 contiguous after Xb
  u16* W0 = Wb;

  dim3 blk(256);
  // one fused conversion: X (2 segs) + wq + wk + wv into Xb..W2 (contiguous)
  conv5_f32_bf16<<<dim3((int)(WSZ / 2048), 5), blk, 0, stream>>>(X, wq, wk, wv, Xb, WSZ);

  // fused Q/K/V projections as ONE GEMM: M=4096, N=6144 (Wq|Wk|Wv), K=2048
  gemm256_qkv<<<dim3(24, 16), dim3(512), 0, stream>>>(
      Xb, Wb, bq, bk, bv, Qw, 2048);

  // causal flash attention; ctx written in-place over Qw (each block reads
  // only its own Q rows/head-cols before writing them)
  attn_fwd<<<dim3(16, 32), blk, 0, stream>>>(Qw, Kw, Vw, Qw);

  // output projection (fp32 out), reuse weight slot 0
  conv_f32_bf16<<<(int)(WSZ / 2048), blk, 0, stream>>>(wo, W0, WSZ);
  gemm_bt_bias<true><<<dim3(16, 32, 1), blk, 0, stream>>>(
      Qw, W0, bo, out, W0, bo, out, W0, bo, out, 4096, 2048, 2048);
}

// Round 2
// 435.683 us; speedup vs baseline: 1.0346x; 1.0346x over previous
//
#include <hip/hip_runtime.h>
#include <stdint.h>

typedef unsigned short u16;
typedef __attribute__((ext_vector_type(8))) short short8;
typedef __attribute__((ext_vector_type(4))) short short4v;
typedef __attribute__((ext_vector_type(4))) float float4v;

union V8u { short8 v; short4v h[2]; u16 u[8]; unsigned w[4]; };

__device__ __forceinline__ u16 f2bf(float f) {
  unsigned u = __float_as_uint(f);
  u = u + 0x7FFFu + ((u >> 16) & 1u);   // round-to-nearest-even
  return (u16)(u >> 16);
}
__device__ __forceinline__ float4v fzero() {
  float4v z = {0.f, 0.f, 0.f, 0.f};
  return z;
}
__device__ __forceinline__ void gl_lds16(const u16* g, u16* l) {
  __builtin_amdgcn_global_load_lds(
      (const __attribute__((address_space(1))) void*)g,
      (__attribute__((address_space(3))) void*)l, 16, 0, 0);
}

#define MFMA16(a, b, c) __builtin_amdgcn_mfma_f32_16x16x32_bf16((a), (b), (c), 0, 0, 0)

// ---------------------------------------------------------------------------
// fp32 -> bf16 for 5 contiguous segments: X (2 segs) + wq,wk,wv. 8 elems/thr.
// ---------------------------------------------------------------------------
__global__ void conv5_f32_bf16(const float* __restrict__ X,
                               const float* __restrict__ w0,
                               const float* __restrict__ w1,
                               const float* __restrict__ w2,
                               u16* __restrict__ dst, long seg) {
  const int y = blockIdx.y;
  const float* s = (y < 2) ? (X + (long)y * seg)
                           : (y == 2 ? w0 : (y == 3 ? w1 : w2));
  u16* d = dst + (long)y * seg;
  const long i = ((long)blockIdx.x * 256 + threadIdx.x) * 8;
  if (i >= seg) return;
  float4 a = *(const float4*)&s[i];
  float4 b = *(const float4*)&s[i + 4];
  V8u o;
  o.u[0] = f2bf(a.x); o.u[1] = f2bf(a.y); o.u[2] = f2bf(a.z); o.u[3] = f2bf(a.w);
  o.u[4] = f2bf(b.x); o.u[5] = f2bf(b.y); o.u[6] = f2bf(b.z); o.u[7] = f2bf(b.w);
  *(short8*)&d[i] = o.v;
}

__global__ void conv_f32_bf16(const float* __restrict__ in, u16* __restrict__ out, long n) {
  const long i = ((long)blockIdx.x * 256 + threadIdx.x) * 8;
  if (i >= n) return;
  float4 a = *(const float4*)&in[i];
  float4 b = *(const float4*)&in[i + 4];
  V8u o;
  o.u[0] = f2bf(a.x); o.u[1] = f2bf(a.y); o.u[2] = f2bf(a.z); o.u[3] = f2bf(a.w);
  o.u[4] = f2bf(b.x); o.u[5] = f2bf(b.y); o.u[6] = f2bf(b.z); o.u[7] = f2bf(b.w);
  *(short8*)&out[i] = o.v;
}

// ---------------------------------------------------------------------------
// Fused QKV GEMM, 256x256 tile, 8 waves, m201-style 8-phase schedule.
//   O[m][n] = sum_k X[m][k]*Wb[n][k] + bias[n],  N = 6144 (Wq|Wk|Wv rows).
//
// LDS: lds[buf2][A/B][half][128 rows x 64 k] bf16 = 128 KiB, 1 block/CU.
// Swizzle (T2): half-tile row-major [128][128B]; byte ^= ((byte>>3)&0x70)
//   (flip 16B-granule index by row&7). Uniform 8 lanes / 16B slot for the
//   b128 fragment reads; global_load_lds dest stays linear, SOURCE is
//   inverse-swizzled (both-sides rule).
// Phases (T3) per K-tile kt (quadrants of the wave's 128x64 C-tile):
//   ph0: stage H(kt+1,B0) | read a(mh0)x8, b0(nh0)x4 | bar | 16 MFMA q00 | bar
//   ph1: stage H(kt+1,A1) | read b1(nh1)x4           | bar | 16 MFMA q01 | bar
//   ph2: stage H(kt+1,B1) | read a(mh1)x8            | bar | 16 MFMA q11 | bar
//   ph3: stage H(kt+2,A0) | vmcnt(2)                 | bar | 16 MFMA q10 | bar
// Counted vmcnt (T4): the ph3 wait retires ALL of kt+1's half-tiles exactly
//   one barrier before kt+1 ph0 reads them, while keeping H(kt+2,A0) in
//   flight -> queue never drains to 0. H(kt+2,A0) targets the CURRENT
//   buffer's A0 region, which is dead after ph2 (A reads end at ph2).
// T5: setprio(1) around each 16-MFMA cluster.
// T1: bijective XCD swizzle on the 384-block 1-D grid (384 % 8 == 0).
// ---------------------------------------------------------------------------
__global__ __launch_bounds__(512, 2) void gemm256_qkv(
    const u16* __restrict__ X, const u16* __restrict__ Wb,
    const float* __restrict__ bq, const float* __restrict__ bk,
    const float* __restrict__ bv, u16* __restrict__ Out, int K)
{
  __shared__ __align__(16) u16 lds[2][2][2][8192];  // [buf][A/B][half][16 KiB]

  const int t = threadIdx.x;            // 0..511
  const int lane = t & 63;
  const int wave = t >> 6;              // 0..7
  const int quad = lane >> 4, l16 = lane & 15;
  const int wm = wave >> 2, wn = wave & 3;   // 2 x 4 wave grid

  // T1: XCD swizzle; 48 blocks/XCD, grouped so B-panels are shared per XCD.
  const int bid = (int)blockIdx.x;
  const int swz = (bid & 7) * 48 + (bid >> 3);
  const int bx = swz >> 4;              // 0..23 (N tiles of 256)
  const int by = swz & 15;              // 0..15 (M tiles of 256)
  const long m0 = (long)by * 256;
  const long n0 = (long)bx * 256;

  // --- staging precompute: dest d = l*8192 + t*16 (linear, swizzled addr);
  //     logical offset o = d ^ ((d>>3)&0x70); row = o>>7, col = (o&127)>>1.
  const u16* pA[2]; const u16* pB[2];
  #pragma unroll
  for (int l = 0; l < 2; ++l) {
    const int d = l * 8192 + t * 16;
    const int o = d ^ ((d >> 3) & 0x70);
    const int r = o >> 7;
    const int c = (o & 127) >> 1;
    pA[l] = X  + (m0 + r) * (long)K + c;
    pB[l] = Wb + (n0 + r) * (long)K + c;
  }

  // --- per-lane swizzled ds_read column offsets (row part added as imm) ----
  int offk[2];
  #pragma unroll
  for (int kk = 0; kk < 2; ++kk)
    offk[kk] = l16 * 128 + ((kk * 64 + quad * 16) ^ ((l16 & 7) << 4));

  float4v acc[8][4];
  #pragma unroll
  for (int i = 0; i < 8; ++i)
    #pragma unroll
    for (int n = 0; n < 4; ++n) acc[i][n] = fzero();

#define STAGE(buf_, mat_, h_, kt_) do {                                        \
    const long ko_ = (long)(h_) * 128 * K + (long)(kt_) * 64;                  \
    gl_lds16(((mat_) ? pB[0] : pA[0]) + ko_, &lds[buf_][mat_][h_][t * 8]);     \
    gl_lds16(((mat_) ? pB[1] : pA[1]) + ko_, &lds[buf_][mat_][h_][4096 + t * 8]); \
  } while (0)

#define BAR() do { asm volatile("s_barrier" ::: "memory");                     \
                   __builtin_amdgcn_sched_barrier(0); } while (0)

  const int NT = K >> 6;   // 32 K-tiles of 64

  // --- prologue: H(0,A0..B1) + H(1,A0); wait all of kt=0 resident ----------
  STAGE(0, 0, 0, 0);
  STAGE(0, 1, 0, 0);
  STAGE(0, 0, 1, 0);
  STAGE(0, 1, 1, 0);
  STAGE(1, 0, 0, (NT > 1) ? 1 : 0);
  asm volatile("s_waitcnt vmcnt(2)" ::: "memory");
  BAR();

  for (int kt = 0; kt < NT; ++kt) {
    const int buf = kt & 1, nb = buf ^ 1;
    const int kc1 = (kt + 1 < NT) ? kt + 1 : NT - 1;
    const int kc2 = (kt + 2 < NT) ? kt + 2 : NT - 1;
    const char* Ab = (const char*)&lds[buf][0][wm][0];
    const char* Bb = (const char*)&lds[buf][1][wn >> 1][0] + (wn & 1) * 8192;

    short8 a[4][2], b0[2][2], b1[2][2];

    // ------------------------------ phase 0 ------------------------------
    STAGE(nb, 1, 0, kc1);                      // H(kt+1, B0)
    #pragma unroll
    for (int i = 0; i < 4; ++i)
      #pragma unroll
      for (int kk = 0; kk < 2; ++kk)
        a[i][kk] = *(const short8*)(Ab + i * 2048 + offk[kk]);          // mh0
    #pragma unroll
    for (int n = 0; n < 2; ++n)
      #pragma unroll
      for (int kk = 0; kk < 2; ++kk)
        b0[n][kk] = *(const short8*)(Bb + n * 2048 + offk[kk]);         // nh0
    BAR();
    __builtin_amdgcn_s_setprio(1);
    #pragma unroll
    for (int i = 0; i < 4; ++i)
      #pragma unroll
      for (int n = 0; n < 2; ++n)
        #pragma unroll
        for (int kk = 0; kk < 2; ++kk)
          acc[i][n] = MFMA16(a[i][kk], b0[n][kk], acc[i][n]);
    __builtin_amdgcn_s_setprio(0);
    BAR();

    // ------------------------------ phase 1 ------------------------------
    STAGE(nb, 0, 1, kc1);                      // H(kt+1, A1)
    #pragma unroll
    for (int n = 0; n < 2; ++n)
      #pragma unroll
      for (int kk = 0; kk < 2; ++kk)
        b1[n][kk] = *(const short8*)(Bb + (2 + n) * 2048 + offk[kk]);   // nh1
    BAR();
    __builtin_amdgcn_s_setprio(1);
    #pragma unroll
    for (int i = 0; i < 4; ++i)
      #pragma unroll
      for (int n = 0; n < 2; ++n)
        #pragma unroll
        for (int kk = 0; kk < 2; ++kk)
          acc[i][2 + n] = MFMA16(a[i][kk], b1[n][kk], acc[i][2 + n]);
    __builtin_amdgcn_s_setprio(0);
    BAR();

    // ------------------------------ phase 2 ------------------------------
    STAGE(nb, 1, 1, kc1);                      // H(kt+1, B1)
    #pragma unroll
    for (int i = 0; i < 4; ++i)
      #pragma unroll
      for (int kk = 0; kk < 2; ++kk)
        a[i][kk] = *(const short8*)(Ab + 8192 + i * 2048 + offk[kk]);   // mh1
    BAR();
    __builtin_amdgcn_s_setprio(1);
    #pragma unroll
    for (int i = 0; i < 4; ++i)
      #pragma unroll
      for (int n = 0; n < 2; ++n)
        #pragma unroll
        for (int kk = 0; kk < 2; ++kk)
          acc[4 + i][2 + n] = MFMA16(a[i][kk], b1[n][kk], acc[4 + i][2 + n]);
    __builtin_amdgcn_s_setprio(0);
    BAR();

    // ------------------------------ phase 3 ------------------------------
    STAGE(buf, 0, 0, kc2);                     // H(kt+2, A0) -> dead region
    asm volatile("s_waitcnt vmcnt(2)" ::: "memory");  // kt+1 fully resident
    BAR();
    __builtin_amdgcn_s_setprio(1);
    #pragma unroll
    for (int i = 0; i < 4; ++i)
      #pragma unroll
      for (int n = 0; n < 2; ++n)
        #pragma unroll
        for (int kk = 0; kk < 2; ++kk)
          acc[4 + i][n] = MFMA16(a[i][kk], b0[n][kk], acc[4 + i][n]);
    __builtin_amdgcn_s_setprio(0);
    BAR();
  }
  asm volatile("s_waitcnt vmcnt(0)" ::: "memory");  // drain tail dummies

#undef STAGE
#undef BAR

  // --- epilogue: bias + bf16 store, Q/K/V selected by fused column ----------
  #pragma unroll
  for (int n = 0; n < 4; ++n) {
    const int cg = (int)n0 + wn * 64 + n * 16 + l16;     // 0..6143
    const int z = cg >> 11, col = cg & 2047;
    const float* Bp = (z == 0) ? bq : (z == 1 ? bk : bv);
    const float bvv = Bp[col];
    u16* Op = Out + (long)z * (4096L * 2048);
    #pragma unroll
    for (int i = 0; i < 8; ++i) {
      const long r0 = m0 + wm * 128 + i * 16 + quad * 4;
      #pragma unroll
      for (int r = 0; r < 4; ++r)
        Op[(r0 + r) * 2048 + col] = f2bf(acc[i][n][r] + bvv);
    }
  }
}

// ---------------------------------------------------------------------------
// GEMM: O[m][n] = sum_k X[m][k]*W[n][k] + bias[n].  bf16 ops, fp32 acc/bias.
// m97 structure. Kept for the output projection (512 balanced blocks).
// ---------------------------------------------------------------------------
template <bool OUTF32>
__global__ __launch_bounds__(256, 2) void gemm_bt_bias(
    const u16* __restrict__ X,
    const u16* __restrict__ W0, const float* __restrict__ B0, void* __restrict__ O0,
    const u16* __restrict__ W1, const float* __restrict__ B1, void* __restrict__ O1,
    const u16* __restrict__ W2, const float* __restrict__ B2, void* __restrict__ O2,
    int M, int N, int K)
{
  const u16* W = W0; const float* Bb = B0; void* Ov = O0;
  if (blockIdx.z == 1) { W = W1; Bb = B1; Ov = O1; }
  else if (blockIdx.z == 2) { W = W2; Bb = B2; Ov = O2; }

  __shared__ u16 As[128 * 32];
  __shared__ u16 Bs[128 * 32];

  const int t = threadIdx.x;
  const int lane = t & 63, wave = t >> 6;
  const int quad = lane >> 4, l16 = lane & 15;
  const int wm = wave >> 1, wn = wave & 1;
  const long m0 = (long)blockIdx.y * 128;
  const long n0 = (long)blockIdx.x * 128;

  const int srow = t >> 2;
  const int scol = (t & 3) * 8;

  float4v acc[4][4];
  #pragma unroll
  for (int i = 0; i < 4; ++i)
    #pragma unroll
    for (int j = 0; j < 4; ++j) acc[i][j] = fzero();

  for (int k0 = 0; k0 < K; k0 += 32) {
    gl_lds16(&X[(m0 + srow) * K + k0 + scol],      &As[t * 8]);
    gl_lds16(&X[(m0 + srow + 64) * K + k0 + scol], &As[t * 8 + 64 * 32]);
    gl_lds16(&W[(n0 + srow) * K + k0 + scol],      &Bs[t * 8]);
    gl_lds16(&W[(n0 + srow + 64) * K + k0 + scol], &Bs[t * 8 + 64 * 32]);
    __syncthreads();

    short8 a[4], b[4];
    #pragma unroll
    for (int mi = 0; mi < 4; ++mi)
      a[mi] = *(const short8*)&As[(wm * 64 + mi * 16 + l16) * 32 + quad * 8];
    #pragma unroll
    for (int ni = 0; ni < 4; ++ni)
      b[ni] = *(const short8*)&Bs[(wn * 64 + ni * 16 + l16) * 32 + quad * 8];
    #pragma unroll
    for (int mi = 0; mi < 4; ++mi)
      #pragma unroll
      for (int ni = 0; ni < 4; ++ni)
        acc[mi][ni] = MFMA16(a[mi], b[ni], acc[mi][ni]);
    __syncthreads();
  }

  #pragma unroll
  for (int ni = 0; ni < 4; ++ni) {
    const long cg = n0 + wn * 64 + ni * 16 + l16;
    const float bv = Bb[cg];
    #pragma unroll
    for (int mi = 0; mi < 4; ++mi) {
      const long rg0 = m0 + wm * 64 + mi * 16 + quad * 4;
      #pragma unroll
      for (int r = 0; r < 4; ++r) {
        const float v = acc[mi][ni][r] + bv;
        if (OUTF32) ((float*)Ov)[(rg0 + r) * N + cg] = v;
        else        ((u16*)Ov)[(rg0 + r) * N + cg] = f2bf(v);
      }
    }
  }
}

// ---------------------------------------------------------------------------
// Causal flash attention, fixed-scale softmax + ones-column row-sum,
// 32 Q rows per wave / 128 Q rows per block. (unchanged this round)
// ---------------------------------------------------------------------------
#define S_LEN 2048
#define HID   2048
#define HD    128

__global__ __launch_bounds__(256, 2) void attn_fwd(
    const u16* __restrict__ Q, const u16* __restrict__ K,
    const u16* __restrict__ V, u16* __restrict__ Ctx)
{
  __shared__ u16 Ks[2][32 * 136];      // K rows natural, pad 8
  __shared__ unsigned Vt[2][128 * 17]; // Vt[c][r/2] = V[2r'][c] | V[2r'+1][c]<<16
  __shared__ u16 Ps[4 * 2 * 512];      // per-wave, per-group P round-trip

  const int t = threadIdx.x;
  const int lane = t & 63, wave = t >> 6;
  const int quad = lane >> 4, l16 = lane & 15;
  const int qb = (int)(gridDim.x - 1 - blockIdx.x) * 128;  // heavy blocks first
  const int b = blockIdx.y >> 4, h = blockIdx.y & 15;

  const long base = (long)b * S_LEN * HID + (long)h * HD;
  const u16* Qp = Q + base;
  const u16* Kp = K + base;
  const u16* Vp = V + base;

  const int sr2 = t >> 4;          // 0..15: rows 2*sr2, 2*sr2+1 of the tile
  const int sc8 = (t & 15) * 8;    // feature col base
  const int wqb = qb + wave * 32;  // wave's first Q row

  // Q fragments for both groups (A-layout: m=lane&15, k=quad*8+j)
  short8 qf[2][4];
  #pragma unroll
  for (int g = 0; g < 2; ++g) {
    const long qr = wqb + g * 16 + l16;
    #pragma unroll
    for (int kk = 0; kk < 4; ++kk)
      qf[g][kk] = *(const short8*)&Qp[qr * HID + kk * 32 + quad * 8];
  }

  short8 onesv;
  {
    V8u ou;
    #pragma unroll
    for (int j = 0; j < 8; ++j) ou.u[j] = 0x3F80;   // bf16 1.0
    onesv = ou.v;
  }

  float4v o[2][9];                 // per group: [0..7] d-groups, [8] row-sum
  #pragma unroll
  for (int g = 0; g < 2; ++g)
    #pragma unroll
    for (int i = 0; i < 9; ++i) o[g][i] = fzero();
  const float SC = 0.08838834764831845f * 1.4426950408889634f; // scale*log2e

  // prefetch tile 0 into regs, commit to buf 0
  short8 kr0, kr1, vv0, vv1;
  {
    const long g = (long)(2 * sr2) * HID + sc8;
    kr0 = *(const short8*)&Kp[g];
    kr1 = *(const short8*)&Kp[g + HID];
    vv0 = *(const short8*)&Vp[g];
    vv1 = *(const short8*)&Vp[g + HID];
  }
  {
    *(short8*)&Ks[0][(2 * sr2) * 136 + sc8]     = kr0;
    *(short8*)&Ks[0][(2 * sr2 + 1) * 136 + sc8] = kr1;
    V8u a, c; a.v = vv0; c.v = vv1;
    #pragma unroll
    for (int j = 0; j < 8; ++j)
      Vt[0][(sc8 + j) * 17 + sr2] = (unsigned)a.u[j] | ((unsigned)c.u[j] << 16);
  }
  __syncthreads();

  const int T = (qb + 128) >> 5;   // number of 32-row KV tiles
  for (int ti = 0; ti < T; ++ti) {
    const int kv0 = ti << 5;
    const int p = ti & 1;

    const bool more = (ti + 1 < T);
    if (more) {
      const long g = (long)(kv0 + 32 + 2 * sr2) * HID + sc8;
      kr0 = *(const short8*)&Kp[g];
      kr1 = *(const short8*)&Kp[g + HID];
      vv0 = *(const short8*)&Vp[g];
      vv1 = *(const short8*)&Vp[g + HID];
    }

    // wave-uniform activity: both groups share it (kv0, wqb both 32-aligned)
    if (kv0 <= wqb) {
      // ---- S = Q . K^T for both groups (kf read once, used twice) ----
      float4v s[2][2];
      #pragma unroll
      for (int g = 0; g < 2; ++g) { s[g][0] = fzero(); s[g][1] = fzero(); }
      #pragma unroll
      for (int ni = 0; ni < 2; ++ni)
        #pragma unroll
        for (int kk = 0; kk < 4; ++kk) {
          short8 kf = *(const short8*)&Ks[p][(ni * 16 + l16) * 136 + kk * 32 + quad * 8];
          s[0][ni] = MFMA16(qf[0][kk], kf, s[0][ni]);
          s[1][ni] = MFMA16(qf[1][kk], kf, s[1][ni]);
        }

      // ---- fixed-scale exp + causal mask + P round-trip per group ----
      const int pb = wave * 1024;
      #pragma unroll
      for (int g = 0; g < 2; ++g) {
        const int qrow0 = wqb + g * 16 + quad * 4;
        #pragma unroll
        for (int r = 0; r < 4; ++r) {
          float s0 = fminf(s[g][0][r] * SC, 80.f);
          float s1 = fminf(s[g][1][r] * SC, 80.f);
          if (kv0 + l16 > qrow0 + r)      s0 = -1e30f;
          if (kv0 + 16 + l16 > qrow0 + r) s1 = -1e30f;
          Ps[pb + g * 512 + (quad * 4 + r) * 32 + l16]      = f2bf(__builtin_amdgcn_exp2f(s0));
          Ps[pb + g * 512 + (quad * 4 + r) * 32 + 16 + l16] = f2bf(__builtin_amdgcn_exp2f(s1));
        }
      }
      __threadfence_block();
      short8 pf0 = *(const short8*)&Ps[pb + l16 * 32 + quad * 8];
      short8 pf1 = *(const short8*)&Ps[pb + 512 + l16 * 32 + quad * 8];

      // ---- O += P . V (vf read once, used twice) ; ones row-sum ----
      #pragma unroll
      for (int dt = 0; dt < 8; ++dt) {
        const unsigned* vp = &Vt[p][(dt * 16 + l16) * 17 + quad * 4];
        V8u vf;
        vf.w[0] = vp[0]; vf.w[1] = vp[1]; vf.w[2] = vp[2]; vf.w[3] = vp[3];
        o[0][dt] = MFMA16(pf0, vf.v, o[0][dt]);
        o[1][dt] = MFMA16(pf1, vf.v, o[1][dt]);
      }
      o[0][8] = MFMA16(pf0, onesv, o[0][8]);
      o[1][8] = MFMA16(pf1, onesv, o[1][8]);
    }

    if (more) {
      *(short8*)&Ks[1 - p][(2 * sr2) * 136 + sc8]     = kr0;
      *(short8*)&Ks[1 - p][(2 * sr2 + 1) * 136 + sc8] = kr1;
      V8u a, c; a.v = vv0; c.v = vv1;
      #pragma unroll
      for (int j = 0; j < 8; ++j)
        Vt[1 - p][(sc8 + j) * 17 + sr2] = (unsigned)a.u[j] | ((unsigned)c.u[j] << 16);
    }
    __syncthreads();
  }

  // ---- epilogue: O / L -> ctx (merged-head layout [B*S][H]) ----
  u16* Cp = Ctx + base;
  #pragma unroll
  for (int g = 0; g < 2; ++g)
    #pragma unroll
    for (int r = 0; r < 4; ++r) {
      const float inv = 1.0f / o[g][8][r];
      const long qr = wqb + g * 16 + quad * 4 + r;
      #pragma unroll
      for (int dt = 0; dt < 8; ++dt)
        Cp[qr * HID + dt * 16 + l16] = f2bf(o[g][dt][r] * inv);
    }
}

// ---------------------------------------------------------------------------
extern "C" void kernel_launch(void* const* d_in, const int* in_sizes, int n_in,
                              void* d_out, int out_size, void* d_ws, size_t ws_size,
                              hipStream_t stream) {
  const float* X  = (const float*)d_in[0];
  const float* wq = (const float*)d_in[1];
  const float* bq = (const float*)d_in[2];
  const float* wk = (const float*)d_in[3];
  const float* bk = (const float*)d_in[4];
  const float* wv = (const float*)d_in[5];
  const float* bv = (const float*)d_in[6];
  const float* wo = (const float*)d_in[7];
  const float* bo = (const float*)d_in[8];
  float* out = (float*)d_out;

  const long HSZ = 4096L * 2048;   // B*S x H
  const long WSZ = 2048L * 2048;
  // ws (bf16 elems): Qw Kw Vw (3x16.8MB) + Xb (16.8MB) + W0..W2 (3x8.4MB)
  u16* Qw = (u16*)d_ws;
  u16* Kw = Qw + HSZ;
  u16* Vw = Kw + HSZ;
  u16* Xb = Vw + HSZ;
  u16* Wb = Xb + HSZ;              // W0,W1,W2 contiguous after Xb
  u16* W0 = Wb;

  dim3 blk(256);
  // one fused conversion: X (2 segs) + wq + wk + wv into Xb..W2 (contiguous)
  conv5_f32_bf16<<<dim3((int)(WSZ / 2048), 5), blk, 0, stream>>>(X, wq, wk, wv, Xb, WSZ);

  // fused Q/K/V projections as ONE GEMM: M=4096, N=6144 (Wq|Wk|Wv), K=2048
  gemm256_qkv<<<dim3(384), dim3(512), 0, stream>>>(
      Xb, Wb, bq, bk, bv, Qw, 2048);

  // causal flash attention; ctx written in-place over Qw (each block reads
  // only its own Q rows/head-cols before writing them)
  attn_fwd<<<dim3(16, 32), blk, 0, stream>>>(Qw, Kw, Vw, Qw);

  // output projection (fp32 out), reuse weight slot 0
  conv_f32_bf16<<<(int)(WSZ / 2048), blk, 0, stream>>>(wo, W0, WSZ);
  gemm_bt_bias<true><<<dim3(16, 32, 1), blk, 0, stream>>>(
      Qw, W0, bo, out, W0, bo, out, W0, bo, out, 4096, 2048, 2048);
}

// Round 3
// 415.128 us; speedup vs baseline: 1.0858x; 1.0495x over previous
//
#include <hip/hip_runtime.h>
#include <stdint.h>

typedef unsigned short u16;
typedef __attribute__((ext_vector_type(8))) short short8;
typedef __attribute__((ext_vector_type(4))) short short4v;
typedef __attribute__((ext_vector_type(4))) float float4v;

union V8u { short8 v; short4v h[2]; u16 u[8]; unsigned w[4]; };

__device__ __forceinline__ u16 f2bf(float f) {
  unsigned u = __float_as_uint(f);
  u = u + 0x7FFFu + ((u >> 16) & 1u);   // round-to-nearest-even
  return (u16)(u >> 16);
}
__device__ __forceinline__ float4v fzero() {
  float4v z = {0.f, 0.f, 0.f, 0.f};
  return z;
}
__device__ __forceinline__ void gl_lds16(const u16* g, u16* l) {
  __builtin_amdgcn_global_load_lds(
      (const __attribute__((address_space(1))) void*)g,
      (__attribute__((address_space(3))) void*)l, 16, 0, 0);
}

#define MFMA16(a, b, c) __builtin_amdgcn_mfma_f32_16x16x32_bf16((a), (b), (c), 0, 0, 0)

// ---------------------------------------------------------------------------
// fp32 -> bf16 for 5 contiguous segments: X (2 segs) + wq,wk,wv. 8 elems/thr.
// ---------------------------------------------------------------------------
__global__ void conv5_f32_bf16(const float* __restrict__ X,
                               const float* __restrict__ w0,
                               const float* __restrict__ w1,
                               const float* __restrict__ w2,
                               u16* __restrict__ dst, long seg) {
  const int y = blockIdx.y;
  const float* s = (y < 2) ? (X + (long)y * seg)
                           : (y == 2 ? w0 : (y == 3 ? w1 : w2));
  u16* d = dst + (long)y * seg;
  const long i = ((long)blockIdx.x * 256 + threadIdx.x) * 8;
  if (i >= seg) return;
  float4 a = *(const float4*)&s[i];
  float4 b = *(const float4*)&s[i + 4];
  V8u o;
  o.u[0] = f2bf(a.x); o.u[1] = f2bf(a.y); o.u[2] = f2bf(a.z); o.u[3] = f2bf(a.w);
  o.u[4] = f2bf(b.x); o.u[5] = f2bf(b.y); o.u[6] = f2bf(b.z); o.u[7] = f2bf(b.w);
  *(short8*)&d[i] = o.v;
}

__global__ void conv_f32_bf16(const float* __restrict__ in, u16* __restrict__ out, long n) {
  const long i = ((long)blockIdx.x * 256 + threadIdx.x) * 8;
  if (i >= n) return;
  float4 a = *(const float4*)&in[i];
  float4 b = *(const float4*)&in[i + 4];
  V8u o;
  o.u[0] = f2bf(a.x); o.u[1] = f2bf(a.y); o.u[2] = f2bf(a.z); o.u[3] = f2bf(a.w);
  o.u[4] = f2bf(b.x); o.u[5] = f2bf(b.y); o.u[6] = f2bf(b.z); o.u[7] = f2bf(b.w);
  *(short8*)&out[i] = o.v;
}

// ---------------------------------------------------------------------------
// Fused QKV GEMM, 256x256 tile, 8 waves, deep-pipelined 4-phase schedule.
//   O[m][n] = sum_k X[m][k]*Wb[n][k] + bias[n],  N = 6144 (Wq|Wk|Wv rows).
//
// LDS: lds[buf2][A/B][half][128 rows x 64 k] bf16 = 128 KiB, 1 block/CU.
// Deep pipeline (T3/T4): during K-tile kt (reading lds[kt&1]), stage K-tile
//   kt+2 into the SAME buffer's dead regions:
//     ph2: stage kt+2 B0,B1  (B regions dead: B reads end at ph1)
//     ph3: stage kt+2 A0,A1  (A regions dead: A reads end at ph2)
//   then s_waitcnt vmcnt(8): retires kt+1's 8 loads (issued one K-tile ago,
//   4-6 phases of flight) while keeping kt+2's 8 in flight. Never drains.
// T2: byte ^= ((byte>>3)&0x70) swizzle, inverse-swizzled global source.
// T5: setprio(1) around each 16-MFMA cluster.
// T1: bijective XCD swizzle on the 384-block 1-D grid (384 % 8 == 0).
// ---------------------------------------------------------------------------
__global__ __launch_bounds__(512, 2) void gemm256_qkv(
    const u16* __restrict__ X, const u16* __restrict__ Wb,
    const float* __restrict__ bq, const float* __restrict__ bk,
    const float* __restrict__ bv, u16* __restrict__ Out, int K)
{
  __shared__ __align__(16) u16 lds[2][2][2][8192];  // [buf][A/B][half][16 KiB]

  const int t = threadIdx.x;            // 0..511
  const int lane = t & 63;
  const int wave = t >> 6;              // 0..7
  const int quad = lane >> 4, l16 = lane & 15;
  const int wm = wave >> 2, wn = wave & 3;   // 2 x 4 wave grid

  // T1: XCD swizzle; 48 blocks/XCD, grouped so B-panels are shared per XCD.
  const int bid = (int)blockIdx.x;
  const int swz = (bid & 7) * 48 + (bid >> 3);
  const int bx = swz >> 4;              // 0..23 (N tiles of 256)
  const int by = swz & 15;              // 0..15 (M tiles of 256)
  const long m0 = (long)by * 256;
  const long n0 = (long)bx * 256;

  // --- staging precompute: dest d = l*8192 + t*16 (linear, swizzled addr);
  //     logical offset o = d ^ ((d>>3)&0x70); row = o>>7, col = (o&127)>>1.
  const u16* pA[2]; const u16* pB[2];
  #pragma unroll
  for (int l = 0; l < 2; ++l) {
    const int d = l * 8192 + t * 16;
    const int o = d ^ ((d >> 3) & 0x70);
    const int r = o >> 7;
    const int c = (o & 127) >> 1;
    pA[l] = X  + (m0 + r) * (long)K + c;
    pB[l] = Wb + (n0 + r) * (long)K + c;
  }

  // --- per-lane swizzled ds_read column offsets (row part added as imm) ----
  int offk[2];
  #pragma unroll
  for (int kk = 0; kk < 2; ++kk)
    offk[kk] = l16 * 128 + ((kk * 64 + quad * 16) ^ ((l16 & 7) << 4));

  float4v acc[8][4];
  #pragma unroll
  for (int i = 0; i < 8; ++i)
    #pragma unroll
    for (int n = 0; n < 4; ++n) acc[i][n] = fzero();

#define STAGE(buf_, mat_, h_, kt_) do {                                        \
    const long ko_ = (long)(h_) * 128 * K + (long)(kt_) * 64;                  \
    gl_lds16(((mat_) ? pB[0] : pA[0]) + ko_, &lds[buf_][mat_][h_][t * 8]);     \
    gl_lds16(((mat_) ? pB[1] : pA[1]) + ko_, &lds[buf_][mat_][h_][4096 + t * 8]); \
  } while (0)

#define BAR() do { asm volatile("s_barrier" ::: "memory");                     \
                   __builtin_amdgcn_sched_barrier(0); } while (0)

  const int NT = K >> 6;   // 32 K-tiles of 64

  // --- prologue: all of kt0 -> buf0, all of kt1 -> buf1 (16 loads) ---------
  STAGE(0, 0, 0, 0);
  STAGE(0, 1, 0, 0);
  STAGE(0, 0, 1, 0);
  STAGE(0, 1, 1, 0);
  STAGE(1, 0, 0, 1);
  STAGE(1, 1, 0, 1);
  STAGE(1, 0, 1, 1);
  STAGE(1, 1, 1, 1);
  asm volatile("s_waitcnt vmcnt(8)" ::: "memory");   // kt0 resident
  BAR();

  for (int kt = 0; kt < NT; ++kt) {
    const int buf = kt & 1;
    const int kc2 = (kt + 2 < NT) ? kt + 2 : NT - 1;
    const char* Ab = (const char*)&lds[buf][0][wm][0];
    const char* Bb = (const char*)&lds[buf][1][wn >> 1][0] + (wn & 1) * 8192;

    short8 a[4][2], b0[2][2], b1[2][2];

    // ------------------------------ phase 0 ------------------------------
    #pragma unroll
    for (int i = 0; i < 4; ++i)
      #pragma unroll
      for (int kk = 0; kk < 2; ++kk)
        a[i][kk] = *(const short8*)(Ab + i * 2048 + offk[kk]);          // mh0
    #pragma unroll
    for (int n = 0; n < 2; ++n)
      #pragma unroll
      for (int kk = 0; kk < 2; ++kk)
        b0[n][kk] = *(const short8*)(Bb + n * 2048 + offk[kk]);         // nh0
    BAR();
    __builtin_amdgcn_s_setprio(1);
    #pragma unroll
    for (int i = 0; i < 4; ++i)
      #pragma unroll
      for (int n = 0; n < 2; ++n)
        #pragma unroll
        for (int kk = 0; kk < 2; ++kk)
          acc[i][n] = MFMA16(a[i][kk], b0[n][kk], acc[i][n]);
    __builtin_amdgcn_s_setprio(0);
    BAR();

    // ------------------------------ phase 1 ------------------------------
    #pragma unroll
    for (int n = 0; n < 2; ++n)
      #pragma unroll
      for (int kk = 0; kk < 2; ++kk)
        b1[n][kk] = *(const short8*)(Bb + (2 + n) * 2048 + offk[kk]);   // nh1
    BAR();
    __builtin_amdgcn_s_setprio(1);
    #pragma unroll
    for (int i = 0; i < 4; ++i)
      #pragma unroll
      for (int n = 0; n < 2; ++n)
        #pragma unroll
        for (int kk = 0; kk < 2; ++kk)
          acc[i][2 + n] = MFMA16(a[i][kk], b1[n][kk], acc[i][2 + n]);
    __builtin_amdgcn_s_setprio(0);
    BAR();

    // ------------------------------ phase 2 ------------------------------
    STAGE(buf, 1, 0, kc2);                     // kt+2 B0 -> dead region
    STAGE(buf, 1, 1, kc2);                     // kt+2 B1 -> dead region
    #pragma unroll
    for (int i = 0; i < 4; ++i)
      #pragma unroll
      for (int kk = 0; kk < 2; ++kk)
        a[i][kk] = *(const short8*)(Ab + 8192 + i * 2048 + offk[kk]);   // mh1
    BAR();
    __builtin_amdgcn_s_setprio(1);
    #pragma unroll
    for (int i = 0; i < 4; ++i)
      #pragma unroll
      for (int n = 0; n < 2; ++n)
        #pragma unroll
        for (int kk = 0; kk < 2; ++kk)
          acc[4 + i][2 + n] = MFMA16(a[i][kk], b1[n][kk], acc[4 + i][2 + n]);
    __builtin_amdgcn_s_setprio(0);
    BAR();

    // ------------------------------ phase 3 ------------------------------
    STAGE(buf, 0, 0, kc2);                     // kt+2 A0 -> dead region
    STAGE(buf, 0, 1, kc2);                     // kt+2 A1 -> dead region
    asm volatile("s_waitcnt vmcnt(8)" ::: "memory");  // kt+1 fully resident
    BAR();
    __builtin_amdgcn_s_setprio(1);
    #pragma unroll
    for (int i = 0; i < 4; ++i)
      #pragma unroll
      for (int n = 0; n < 2; ++n)
        #pragma unroll
        for (int kk = 0; kk < 2; ++kk)
          acc[4 + i][n] = MFMA16(a[i][kk], b0[n][kk], acc[4 + i][n]);
    __builtin_amdgcn_s_setprio(0);
    BAR();
  }
  asm volatile("s_waitcnt vmcnt(0)" ::: "memory");  // drain tail dummies

#undef STAGE
#undef BAR

  // --- epilogue: bias + bf16 store, Q/K/V selected by fused column ----------
  #pragma unroll
  for (int n = 0; n < 4; ++n) {
    const int cg = (int)n0 + wn * 64 + n * 16 + l16;     // 0..6143
    const int z = cg >> 11, col = cg & 2047;
    const float* Bp = (z == 0) ? bq : (z == 1 ? bk : bv);
    const float bvv = Bp[col];
    u16* Op = Out + (long)z * (4096L * 2048);
    #pragma unroll
    for (int i = 0; i < 8; ++i) {
      const long r0 = m0 + wm * 128 + i * 16 + quad * 4;
      #pragma unroll
      for (int r = 0; r < 4; ++r)
        Op[(r0 + r) * 2048 + col] = f2bf(acc[i][n][r] + bvv);
    }
  }
}

// ---------------------------------------------------------------------------
// GEMM: O[m][n] = sum_k X[m][k]*W[n][k] + bias[n].  bf16 ops, fp32 acc/bias.
// m97 structure. Kept for the output projection (512 balanced blocks).
// ---------------------------------------------------------------------------
template <bool OUTF32>
__global__ __launch_bounds__(256, 2) void gemm_bt_bias(
    const u16* __restrict__ X,
    const u16* __restrict__ W0, const float* __restrict__ B0, void* __restrict__ O0,
    const u16* __restrict__ W1, const float* __restrict__ B1, void* __restrict__ O1,
    const u16* __restrict__ W2, const float* __restrict__ B2, void* __restrict__ O2,
    int M, int N, int K)
{
  const u16* W = W0; const float* Bb = B0; void* Ov = O0;
  if (blockIdx.z == 1) { W = W1; Bb = B1; Ov = O1; }
  else if (blockIdx.z == 2) { W = W2; Bb = B2; Ov = O2; }

  __shared__ u16 As[128 * 32];
  __shared__ u16 Bs[128 * 32];

  const int t = threadIdx.x;
  const int lane = t & 63, wave = t >> 6;
  const int quad = lane >> 4, l16 = lane & 15;
  const int wm = wave >> 1, wn = wave & 1;
  const long m0 = (long)blockIdx.y * 128;
  const long n0 = (long)blockIdx.x * 128;

  const int srow = t >> 2;
  const int scol = (t & 3) * 8;

  float4v acc[4][4];
  #pragma unroll
  for (int i = 0; i < 4; ++i)
    #pragma unroll
    for (int j = 0; j < 4; ++j) acc[i][j] = fzero();

  for (int k0 = 0; k0 < K; k0 += 32) {
    gl_lds16(&X[(m0 + srow) * K + k0 + scol],      &As[t * 8]);
    gl_lds16(&X[(m0 + srow + 64) * K + k0 + scol], &As[t * 8 + 64 * 32]);
    gl_lds16(&W[(n0 + srow) * K + k0 + scol],      &Bs[t * 8]);
    gl_lds16(&W[(n0 + srow + 64) * K + k0 + scol], &Bs[t * 8 + 64 * 32]);
    __syncthreads();

    short8 a[4], b[4];
    #pragma unroll
    for (int mi = 0; mi < 4; ++mi)
      a[mi] = *(const short8*)&As[(wm * 64 + mi * 16 + l16) * 32 + quad * 8];
    #pragma unroll
    for (int ni = 0; ni < 4; ++ni)
      b[ni] = *(const short8*)&Bs[(wn * 64 + ni * 16 + l16) * 32 + quad * 8];
    #pragma unroll
    for (int mi = 0; mi < 4; ++mi)
      #pragma unroll
      for (int ni = 0; ni < 4; ++ni)
        acc[mi][ni] = MFMA16(a[mi], b[ni], acc[mi][ni]);
    __syncthreads();
  }

  #pragma unroll
  for (int ni = 0; ni < 4; ++ni) {
    const long cg = n0 + wn * 64 + ni * 16 + l16;
    const float bv = Bb[cg];
    #pragma unroll
    for (int mi = 0; mi < 4; ++mi) {
      const long rg0 = m0 + wm * 64 + mi * 16 + quad * 4;
      #pragma unroll
      for (int r = 0; r < 4; ++r) {
        const float v = acc[mi][ni][r] + bv;
        if (OUTF32) ((float*)Ov)[(rg0 + r) * N + cg] = v;
        else        ((u16*)Ov)[(rg0 + r) * N + cg] = f2bf(v);
      }
    }
  }
}

// ---------------------------------------------------------------------------
// Causal flash attention, fixed-scale softmax + ones-column row-sum,
// 32 Q rows per wave / 128 Q rows per pass.
// BALANCED: grid.x = 8; block x sequentially processes Q-tile (15-x) [heavy]
// then Q-tile (x) [light] -> uniform 17 KV-tile-units per block (was 1..16,
// ~53% utilization). In-place Ctx-over-Qw stays safe: heavy passes write
// rows 1024..2047, light passes read rows 0..1023 (disjoint), and each
// block reads only its own rows/head-cols before writing them.
// ---------------------------------------------------------------------------
#define S_LEN 2048
#define HID   2048
#define HD    128

__global__ __launch_bounds__(256, 2) void attn_fwd(
    const u16* __restrict__ Q, const u16* __restrict__ K,
    const u16* __restrict__ V, u16* __restrict__ Ctx)
{
  __shared__ u16 Ks[2][32 * 136];      // K rows natural, pad 8
  __shared__ unsigned Vt[2][128 * 17]; // Vt[c][r/2] = V[2r'][c] | V[2r'+1][c]<<16
  __shared__ u16 Ps[4 * 2 * 512];      // per-wave, per-group P round-trip

  const int t = threadIdx.x;
  const int lane = t & 63, wave = t >> 6;
  const int quad = lane >> 4, l16 = lane & 15;
  const int b = blockIdx.y >> 4, h = blockIdx.y & 15;

  const long base = (long)b * S_LEN * HID + (long)h * HD;
  const u16* Qp = Q + base;
  const u16* Kp = K + base;
  const u16* Vp = V + base;
  u16* Cp = Ctx + base;

  const int sr2 = t >> 4;          // 0..15: rows 2*sr2, 2*sr2+1 of the tile
  const int sc8 = (t & 15) * 8;    // feature col base

  short8 onesv;
  {
    V8u ou;
    #pragma unroll
    for (int j = 0; j < 8; ++j) ou.u[j] = 0x3F80;   // bf16 1.0
    onesv = ou.v;
  }
  const float SC = 0.08838834764831845f * 1.4426950408889634f; // scale*log2e

  for (int pass = 0; pass < 2; ++pass) {
    const int qb = (pass ? (int)blockIdx.x : 15 - (int)blockIdx.x) * 128;
    const int wqb = qb + wave * 32;  // wave's first Q row

    // Q fragments for both groups (A-layout: m=lane&15, k=quad*8+j)
    short8 qf[2][4];
    #pragma unroll
    for (int g = 0; g < 2; ++g) {
      const long qr = wqb + g * 16 + l16;
      #pragma unroll
      for (int kk = 0; kk < 4; ++kk)
        qf[g][kk] = *(const short8*)&Qp[qr * HID + kk * 32 + quad * 8];
    }

    float4v o[2][9];                 // per group: [0..7] d-groups, [8] row-sum
    #pragma unroll
    for (int g = 0; g < 2; ++g)
      #pragma unroll
      for (int i = 0; i < 9; ++i) o[g][i] = fzero();

    // prefetch tile 0 into regs, commit to buf 0
    short8 kr0, kr1, vv0, vv1;
    {
      const long g = (long)(2 * sr2) * HID + sc8;
      kr0 = *(const short8*)&Kp[g];
      kr1 = *(const short8*)&Kp[g + HID];
      vv0 = *(const short8*)&Vp[g];
      vv1 = *(const short8*)&Vp[g + HID];
    }
    {
      *(short8*)&Ks[0][(2 * sr2) * 136 + sc8]     = kr0;
      *(short8*)&Ks[0][(2 * sr2 + 1) * 136 + sc8] = kr1;
      V8u a, c; a.v = vv0; c.v = vv1;
      #pragma unroll
      for (int j = 0; j < 8; ++j)
        Vt[0][(sc8 + j) * 17 + sr2] = (unsigned)a.u[j] | ((unsigned)c.u[j] << 16);
    }
    __syncthreads();

    const int T = (qb + 128) >> 5;   // number of 32-row KV tiles
    for (int ti = 0; ti < T; ++ti) {
      const int kv0 = ti << 5;
      const int p = ti & 1;

      const bool more = (ti + 1 < T);
      if (more) {
        const long g = (long)(kv0 + 32 + 2 * sr2) * HID + sc8;
        kr0 = *(const short8*)&Kp[g];
        kr1 = *(const short8*)&Kp[g + HID];
        vv0 = *(const short8*)&Vp[g];
        vv1 = *(const short8*)&Vp[g + HID];
      }

      // wave-uniform activity: both groups share it (kv0, wqb 32-aligned)
      if (kv0 <= wqb) {
        // ---- S = Q . K^T for both groups (kf read once, used twice) ----
        float4v s[2][2];
        #pragma unroll
        for (int g = 0; g < 2; ++g) { s[g][0] = fzero(); s[g][1] = fzero(); }
        #pragma unroll
        for (int ni = 0; ni < 2; ++ni)
          #pragma unroll
          for (int kk = 0; kk < 4; ++kk) {
            short8 kf = *(const short8*)&Ks[p][(ni * 16 + l16) * 136 + kk * 32 + quad * 8];
            s[0][ni] = MFMA16(qf[0][kk], kf, s[0][ni]);
            s[1][ni] = MFMA16(qf[1][kk], kf, s[1][ni]);
          }

        // ---- fixed-scale exp + causal mask + P round-trip per group ----
        const int pb = wave * 1024;
        #pragma unroll
        for (int g = 0; g < 2; ++g) {
          const int qrow0 = wqb + g * 16 + quad * 4;
          #pragma unroll
          for (int r = 0; r < 4; ++r) {
            float s0 = fminf(s[g][0][r] * SC, 80.f);
            float s1 = fminf(s[g][1][r] * SC, 80.f);
            if (kv0 + l16 > qrow0 + r)      s0 = -1e30f;
            if (kv0 + 16 + l16 > qrow0 + r) s1 = -1e30f;
            Ps[pb + g * 512 + (quad * 4 + r) * 32 + l16]      = f2bf(__builtin_amdgcn_exp2f(s0));
            Ps[pb + g * 512 + (quad * 4 + r) * 32 + 16 + l16] = f2bf(__builtin_amdgcn_exp2f(s1));
          }
        }
        __threadfence_block();
        short8 pf0 = *(const short8*)&Ps[pb + l16 * 32 + quad * 8];
        short8 pf1 = *(const short8*)&Ps[pb + 512 + l16 * 32 + quad * 8];

        // ---- O += P . V (vf read once, used twice) ; ones row-sum ----
        #pragma unroll
        for (int dt = 0; dt < 8; ++dt) {
          const unsigned* vp = &Vt[p][(dt * 16 + l16) * 17 + quad * 4];
          V8u vf;
          vf.w[0] = vp[0]; vf.w[1] = vp[1]; vf.w[2] = vp[2]; vf.w[3] = vp[3];
          o[0][dt] = MFMA16(pf0, vf.v, o[0][dt]);
          o[1][dt] = MFMA16(pf1, vf.v, o[1][dt]);
        }
        o[0][8] = MFMA16(pf0, onesv, o[0][8]);
        o[1][8] = MFMA16(pf1, onesv, o[1][8]);
      }

      if (more) {
        *(short8*)&Ks[1 - p][(2 * sr2) * 136 + sc8]     = kr0;
        *(short8*)&Ks[1 - p][(2 * sr2 + 1) * 136 + sc8] = kr1;
        V8u a, c; a.v = vv0; c.v = vv1;
        #pragma unroll
        for (int j = 0; j < 8; ++j)
          Vt[1 - p][(sc8 + j) * 17 + sr2] = (unsigned)a.u[j] | ((unsigned)c.u[j] << 16);
      }
      __syncthreads();
    }

    // ---- epilogue: O / L -> ctx (merged-head layout [B*S][H]) ----
    #pragma unroll
    for (int g = 0; g < 2; ++g)
      #pragma unroll
      for (int r = 0; r < 4; ++r) {
        const float inv = 1.0f / o[g][8][r];
        const long qr = wqb + g * 16 + quad * 4 + r;
        #pragma unroll
        for (int dt = 0; dt < 8; ++dt)
          Cp[qr * HID + dt * 16 + l16] = f2bf(o[g][dt][r] * inv);
      }
  }
}

// ---------------------------------------------------------------------------
extern "C" void kernel_launch(void* const* d_in, const int* in_sizes, int n_in,
                              void* d_out, int out_size, void* d_ws, size_t ws_size,
                              hipStream_t stream) {
  const float* X  = (const float*)d_in[0];
  const float* wq = (const float*)d_in[1];
  const float* bq = (const float*)d_in[2];
  const float* wk = (const float*)d_in[3];
  const float* bk = (const float*)d_in[4];
  const float* wv = (const float*)d_in[5];
  const float* bv = (const float*)d_in[6];
  const float* wo = (const float*)d_in[7];
  const float* bo = (const float*)d_in[8];
  float* out = (float*)d_out;

  const long HSZ = 4096L * 2048;   // B*S x H
  const long WSZ = 2048L * 2048;
  // ws (bf16 elems): Qw Kw Vw (3x16.8MB) + Xb (16.8MB) + W0..W2 (3x8.4MB)
  u16* Qw = (u16*)d_ws;
  u16* Kw = Qw + HSZ;
  u16* Vw = Kw + HSZ;
  u16* Xb = Vw + HSZ;
  u16* Wb = Xb + HSZ;              // W0,W1,W2 contiguous after Xb
  u16* W0 = Wb;

  dim3 blk(256);
  // one fused conversion: X (2 segs) + wq + wk + wv into Xb..W2 (contiguous)
  conv5_f32_bf16<<<dim3((int)(WSZ / 2048), 5), blk, 0, stream>>>(X, wq, wk, wv, Xb, WSZ);

  // fused Q/K/V projections as ONE GEMM: M=4096, N=6144 (Wq|Wk|Wv), K=2048
  gemm256_qkv<<<dim3(384), dim3(512), 0, stream>>>(
      Xb, Wb, bq, bk, bv, Qw, 2048);

  // causal flash attention (balanced heavy+light pairs); ctx in-place over Qw
  attn_fwd<<<dim3(8, 32), blk, 0, stream>>>(Qw, Kw, Vw, Qw);

  // output projection (fp32 out), reuse weight slot 0
  conv_f32_bf16<<<(int)(WSZ / 2048), blk, 0, stream>>>(wo, W0, WSZ);
  gemm_bt_bias<true><<<dim3(16, 32, 1), blk, 0, stream>>>(
      Qw, W0, bo, out, W0, bo, out, W0, bo, out, 4096, 2048, 2048);
}

// Round 4
// 393.997 us; speedup vs baseline: 1.1440x; 1.0536x over previous
//
#include <hip/hip_runtime.h>
#include <stdint.h>

typedef unsigned short u16;
typedef __attribute__((ext_vector_type(8))) short short8;
typedef __attribute__((ext_vector_type(4))) short short4v;
typedef __attribute__((ext_vector_type(4))) float float4v;

union V8u { short8 v; short4v h[2]; u16 u[8]; unsigned w[4]; };

__device__ __forceinline__ u16 f2bf(float f) {
  unsigned u = __float_as_uint(f);
  u = u + 0x7FFFu + ((u >> 16) & 1u);   // round-to-nearest-even
  return (u16)(u >> 16);
}
__device__ __forceinline__ float4v fzero() {
  float4v z = {0.f, 0.f, 0.f, 0.f};
  return z;
}
__device__ __forceinline__ void gl_lds16(const u16* g, u16* l) {
  __builtin_amdgcn_global_load_lds(
      (const __attribute__((address_space(1))) void*)g,
      (__attribute__((address_space(3))) void*)l, 16, 0, 0);
}

#define MFMA16(a, b, c) __builtin_amdgcn_mfma_f32_16x16x32_bf16((a), (b), (c), 0, 0, 0)

// ---------------------------------------------------------------------------
// fp32 -> bf16 for 5 contiguous segments: X (2 segs) + wq,wk,wv. 8 elems/thr.
// ---------------------------------------------------------------------------
__global__ void conv5_f32_bf16(const float* __restrict__ X,
                               const float* __restrict__ w0,
                               const float* __restrict__ w1,
                               const float* __restrict__ w2,
                               u16* __restrict__ dst, long seg) {
  const int y = blockIdx.y;
  const float* s = (y < 2) ? (X + (long)y * seg)
                           : (y == 2 ? w0 : (y == 3 ? w1 : w2));
  u16* d = dst + (long)y * seg;
  const long i = ((long)blockIdx.x * 256 + threadIdx.x) * 8;
  if (i >= seg) return;
  float4 a = *(const float4*)&s[i];
  float4 b = *(const float4*)&s[i + 4];
  V8u o;
  o.u[0] = f2bf(a.x); o.u[1] = f2bf(a.y); o.u[2] = f2bf(a.z); o.u[3] = f2bf(a.w);
  o.u[4] = f2bf(b.x); o.u[5] = f2bf(b.y); o.u[6] = f2bf(b.z); o.u[7] = f2bf(b.w);
  *(short8*)&d[i] = o.v;
}

__global__ void conv_f32_bf16(const float* __restrict__ in, u16* __restrict__ out, long n) {
  const long i = ((long)blockIdx.x * 256 + threadIdx.x) * 8;
  if (i >= n) return;
  float4 a = *(const float4*)&in[i];
  float4 b = *(const float4*)&in[i + 4];
  V8u o;
  o.u[0] = f2bf(a.x); o.u[1] = f2bf(a.y); o.u[2] = f2bf(a.z); o.u[3] = f2bf(a.w);
  o.u[4] = f2bf(b.x); o.u[5] = f2bf(b.y); o.u[6] = f2bf(b.z); o.u[7] = f2bf(b.w);
  *(short8*)&out[i] = o.v;
}

// ---------------------------------------------------------------------------
// Balanced GEMM: O[m][n] = sum_k X[m][k]*W[n][k] + bias[n].
// BM=128, BN=256, BK=64, 512 thr / 8 waves (2M x 4N), per-wave 64x64.
//   QKV use:  M=4096, N=6144 (Wq|Wk|Wv rows) -> grid 768 = 3 blocks/CU exact.
//   Out-proj: M=4096, N=2048               -> grid 256 = 1 block/CU exact.
// LDS: lds[3 bufs][A(128x64) | Blo(128x64) | Bup(128x64)] = 144 KiB.
// Triple buffer (T3/T4): at kt {ph0: stage A+Blo of kt+2, ph1: stage Bup},
//   target buf (kt+2)%3 (last read finished at kt-1 ph1-end barrier).
//   One s_waitcnt vmcnt(6) per K-tile (at kt ph1) retires kt+1's 6 loads,
//   issued >=3 phases earlier; queue never drains in the main loop.
// T2: byte ^= ((byte>>3)&0x70) swizzle (involution); inverse-swizzled global
//   source, swizzled ds_read col offsets -> 0 bank conflicts (verified R1-3).
// T5: setprio(1) around each 16-MFMA cluster.
// T1: bijective XCD swizzle; per-XCD chunk shares B-panels in its L2.
// Epilogue: bias add; segment z = col>>11 selects (bias, output segment) so
//   the fused Wq|Wk|Wv output lands in Qw/Kw/Vw; OUTF32 for the final proj.
// ---------------------------------------------------------------------------
template <bool OUTF32>
__global__ __launch_bounds__(512, 2) void gemm_bal(
    const u16* __restrict__ X, const u16* __restrict__ Wb,
    const float* __restrict__ b0, const float* __restrict__ b1,
    const float* __restrict__ b2, void* __restrict__ Out,
    int K, int cpx)
{
  __shared__ __align__(16) u16 lds[3][3][8192];  // [buf][A|Blo|Bup][16 KiB]

  const int t = threadIdx.x;            // 0..511
  const int lane = t & 63;
  const int wave = t >> 6;              // 0..7
  const int quad = lane >> 4, l16 = lane & 15;
  const int wm = wave >> 2, wn = wave & 3;   // 2 x 4 wave grid

  // T1: XCD swizzle (grid % 8 == 0; cpx = grid/8). by fast -> A-col reuse,
  // bx chunked per XCD -> B-panel L2 reuse.
  const int bid = (int)blockIdx.x;
  const int swz = (bid & 7) * cpx + (bid >> 3);
  const int by = swz & 31;              // 32 M-tiles of 128
  const int bx = swz >> 5;              // N-tiles of 256
  const long m0 = (long)by * 128;
  const long n0 = (long)bx * 256;

  // --- staging precompute: dest d = l*8192 + t*16 (linear); logical
  //     o = d ^ ((d>>3)&0x70); row = o>>7 (l=0: 0..63, l=1: 64..127),
  //     col elem = (o&127)>>1.
  const u16* pA[2]; const u16* pBl[2]; const u16* pBu[2];
  #pragma unroll
  for (int l = 0; l < 2; ++l) {
    const int d = l * 8192 + t * 16;
    const int o = d ^ ((d >> 3) & 0x70);
    const int r = o >> 7;
    const int c = (o & 127) >> 1;
    pA[l]  = X  + (m0 + r) * (long)K + c;
    pBl[l] = Wb + (n0 + r) * (long)K + c;
    pBu[l] = Wb + (n0 + 128 + r) * (long)K + c;
  }

  // --- per-lane swizzled ds_read byte offsets (row base added separately) --
  int offk[2];
  #pragma unroll
  for (int kk = 0; kk < 2; ++kk)
    offk[kk] = l16 * 128 + ((kk * 64 + quad * 16) ^ ((l16 & 7) << 4));

  float4v acc[4][4];
  #pragma unroll
  for (int i = 0; i < 4; ++i)
    #pragma unroll
    for (int n = 0; n < 4; ++n) acc[i][n] = fzero();

#define STG(buf_, reg_, ptr_, kt_) do {                                        \
    gl_lds16(ptr_[0] + (long)(kt_) * 64, &lds[buf_][reg_][t * 8]);             \
    gl_lds16(ptr_[1] + (long)(kt_) * 64, &lds[buf_][reg_][4096 + t * 8]);      \
  } while (0)

#define BAR() do { asm volatile("s_barrier" ::: "memory");                     \
                   __builtin_amdgcn_sched_barrier(0); } while (0)

  const int NT = K >> 6;   // K-tiles of 64 (32 here)

  // --- prologue: kt0 -> buf0, kt1 -> buf1 (12 loads); wait kt0 resident ----
  STG(0, 0, pA, 0);  STG(0, 1, pBl, 0);  STG(0, 2, pBu, 0);
  STG(1, 0, pA, 1);  STG(1, 1, pBl, 1);  STG(1, 2, pBu, 1);
  asm volatile("s_waitcnt vmcnt(6)" ::: "memory");
  BAR();

  int buf = 0, sb = 2;   // current buffer, stage buffer (kt+2)%3
  for (int kt = 0; kt < NT; ++kt) {
    const int s2 = (kt + 2 < NT) ? kt + 2 : NT - 1;  // tail: dummy into dead buf
    const char* Ab = (const char*)&lds[buf][0][0] + wm * 8192;
    const char* Bb = (const char*)&lds[buf][1 + (wn >> 1)][0] + (wn & 1) * 8192;

    short8 a[4][2], b[4][2];

    // ------------------------------ phase 0 ------------------------------
    STG(sb, 0, pA, s2);
    STG(sb, 1, pBl, s2);
    #pragma unroll
    for (int i = 0; i < 4; ++i)
      #pragma unroll
      for (int kk = 0; kk < 2; ++kk)
        a[i][kk] = *(const short8*)(Ab + i * 2048 + offk[kk]);
    #pragma unroll
    for (int n = 0; n < 2; ++n)
      #pragma unroll
      for (int kk = 0; kk < 2; ++kk)
        b[n][kk] = *(const short8*)(Bb + n * 2048 + offk[kk]);
    BAR();
    __builtin_amdgcn_s_setprio(1);
    #pragma unroll
    for (int i = 0; i < 4; ++i)
      #pragma unroll
      for (int n = 0; n < 2; ++n)
        #pragma unroll
        for (int kk = 0; kk < 2; ++kk)
          acc[i][n] = MFMA16(a[i][kk], b[n][kk], acc[i][n]);
    __builtin_amdgcn_s_setprio(0);
    BAR();

    // ------------------------------ phase 1 ------------------------------
    STG(sb, 2, pBu, s2);
    #pragma unroll
    for (int n = 2; n < 4; ++n)
      #pragma unroll
      for (int kk = 0; kk < 2; ++kk)
        b[n][kk] = *(const short8*)(Bb + n * 2048 + offk[kk]);
    asm volatile("s_waitcnt vmcnt(6)" ::: "memory");  // kt+1 fully resident
    BAR();
    __builtin_amdgcn_s_setprio(1);
    #pragma unroll
    for (int i = 0; i < 4; ++i)
      #pragma unroll
      for (int n = 2; n < 4; ++n)
        #pragma unroll
        for (int kk = 0; kk < 2; ++kk)
          acc[i][n] = MFMA16(a[i][kk], b[n][kk], acc[i][n]);
    __builtin_amdgcn_s_setprio(0);
    BAR();

    buf = (buf == 2) ? 0 : buf + 1;
    sb  = (sb  == 2) ? 0 : sb  + 1;
  }

#undef STG
#undef BAR

  // --- epilogue: bias + store; segment z = col>>11 -------------------------
  #pragma unroll
  for (int n = 0; n < 4; ++n) {
    const int cg = (int)n0 + wn * 64 + n * 16 + l16;
    const int z = cg >> 11, col = cg & 2047;
    const float* Bp = (z == 0) ? b0 : (z == 1 ? b1 : b2);
    const float bvv = Bp[col];
    #pragma unroll
    for (int i = 0; i < 4; ++i) {
      const long r0 = m0 + wm * 64 + i * 16 + quad * 4;
      #pragma unroll
      for (int r = 0; r < 4; ++r) {
        const long off = (long)z * (4096L * 2048) + (r0 + r) * 2048 + col;
        const float v = acc[i][n][r] + bvv;
        if (OUTF32) ((float*)Out)[off] = v;
        else        ((u16*)Out)[off] = f2bf(v);
      }
    }
  }
}

// ---------------------------------------------------------------------------
// Causal flash attention, fixed-scale softmax + ones-column row-sum,
// 32 Q rows per wave / 128 Q rows per pass.
// BALANCED: grid.x = 8; block x sequentially processes Q-tile (15-x) [heavy]
// then Q-tile (x) [light] -> uniform 17 KV-tile-units per block. In-place
// Ctx-over-Qw stays safe: heavy passes write rows 1024..2047, light passes
// read rows 0..1023 (disjoint), and each block reads only its own rows /
// head-cols before writing them.
// ---------------------------------------------------------------------------
#define S_LEN 2048
#define HID   2048
#define HD    128

__global__ __launch_bounds__(256, 2) void attn_fwd(
    const u16* __restrict__ Q, const u16* __restrict__ K,
    const u16* __restrict__ V, u16* __restrict__ Ctx)
{
  __shared__ u16 Ks[2][32 * 136];      // K rows natural, pad 8
  __shared__ unsigned Vt[2][128 * 17]; // Vt[c][r/2] = V[2r'][c] | V[2r'+1][c]<<16
  __shared__ u16 Ps[4 * 2 * 512];      // per-wave, per-group P round-trip

  const int t = threadIdx.x;
  const int lane = t & 63, wave = t >> 6;
  const int quad = lane >> 4, l16 = lane & 15;
  const int b = blockIdx.y >> 4, h = blockIdx.y & 15;

  const long base = (long)b * S_LEN * HID + (long)h * HD;
  const u16* Qp = Q + base;
  const u16* Kp = K + base;
  const u16* Vp = V + base;
  u16* Cp = Ctx + base;

  const int sr2 = t >> 4;          // 0..15: rows 2*sr2, 2*sr2+1 of the tile
  const int sc8 = (t & 15) * 8;    // feature col base

  short8 onesv;
  {
    V8u ou;
    #pragma unroll
    for (int j = 0; j < 8; ++j) ou.u[j] = 0x3F80;   // bf16 1.0
    onesv = ou.v;
  }
  const float SC = 0.08838834764831845f * 1.4426950408889634f; // scale*log2e

  for (int pass = 0; pass < 2; ++pass) {
    const int qb = (pass ? (int)blockIdx.x : 15 - (int)blockIdx.x) * 128;
    const int wqb = qb + wave * 32;  // wave's first Q row

    // Q fragments for both groups (A-layout: m=lane&15, k=quad*8+j)
    short8 qf[2][4];
    #pragma unroll
    for (int g = 0; g < 2; ++g) {
      const long qr = wqb + g * 16 + l16;
      #pragma unroll
      for (int kk = 0; kk < 4; ++kk)
        qf[g][kk] = *(const short8*)&Qp[qr * HID + kk * 32 + quad * 8];
    }

    float4v o[2][9];                 // per group: [0..7] d-groups, [8] row-sum
    #pragma unroll
    for (int g = 0; g < 2; ++g)
      #pragma unroll
      for (int i = 0; i < 9; ++i) o[g][i] = fzero();

    // prefetch tile 0 into regs, commit to buf 0
    short8 kr0, kr1, vv0, vv1;
    {
      const long g = (long)(2 * sr2) * HID + sc8;
      kr0 = *(const short8*)&Kp[g];
      kr1 = *(const short8*)&Kp[g + HID];
      vv0 = *(const short8*)&Vp[g];
      vv1 = *(const short8*)&Vp[g + HID];
    }
    {
      *(short8*)&Ks[0][(2 * sr2) * 136 + sc8]     = kr0;
      *(short8*)&Ks[0][(2 * sr2 + 1) * 136 + sc8] = kr1;
      V8u a, c; a.v = vv0; c.v = vv1;
      #pragma unroll
      for (int j = 0; j < 8; ++j)
        Vt[0][(sc8 + j) * 17 + sr2] = (unsigned)a.u[j] | ((unsigned)c.u[j] << 16);
    }
    __syncthreads();

    const int T = (qb + 128) >> 5;   // number of 32-row KV tiles
    for (int ti = 0; ti < T; ++ti) {
      const int kv0 = ti << 5;
      const int p = ti & 1;

      const bool more = (ti + 1 < T);
      if (more) {
        const long g = (long)(kv0 + 32 + 2 * sr2) * HID + sc8;
        kr0 = *(const short8*)&Kp[g];
        kr1 = *(const short8*)&Kp[g + HID];
        vv0 = *(const short8*)&Vp[g];
        vv1 = *(const short8*)&Vp[g + HID];
      }

      // wave-uniform activity: both groups share it (kv0, wqb 32-aligned)
      if (kv0 <= wqb) {
        // ---- S = Q . K^T for both groups (kf read once, used twice) ----
        float4v s[2][2];
        #pragma unroll
        for (int g = 0; g < 2; ++g) { s[g][0] = fzero(); s[g][1] = fzero(); }
        #pragma unroll
        for (int ni = 0; ni < 2; ++ni)
          #pragma unroll
          for (int kk = 0; kk < 4; ++kk) {
            short8 kf = *(const short8*)&Ks[p][(ni * 16 + l16) * 136 + kk * 32 + quad * 8];
            s[0][ni] = MFMA16(qf[0][kk], kf, s[0][ni]);
            s[1][ni] = MFMA16(qf[1][kk], kf, s[1][ni]);
          }

        // ---- fixed-scale exp + causal mask + P round-trip per group ----
        const int pb = wave * 1024;
        #pragma unroll
        for (int g = 0; g < 2; ++g) {
          const int qrow0 = wqb + g * 16 + quad * 4;
          #pragma unroll
          for (int r = 0; r < 4; ++r) {
            float s0 = fminf(s[g][0][r] * SC, 80.f);
            float s1 = fminf(s[g][1][r] * SC, 80.f);
            if (kv0 + l16 > qrow0 + r)      s0 = -1e30f;
            if (kv0 + 16 + l16 > qrow0 + r) s1 = -1e30f;
            Ps[pb + g * 512 + (quad * 4 + r) * 32 + l16]      = f2bf(__builtin_amdgcn_exp2f(s0));
            Ps[pb + g * 512 + (quad * 4 + r) * 32 + 16 + l16] = f2bf(__builtin_amdgcn_exp2f(s1));
          }
        }
        __threadfence_block();
        short8 pf0 = *(const short8*)&Ps[pb + l16 * 32 + quad * 8];
        short8 pf1 = *(const short8*)&Ps[pb + 512 + l16 * 32 + quad * 8];

        // ---- O += P . V (vf read once, used twice) ; ones row-sum ----
        #pragma unroll
        for (int dt = 0; dt < 8; ++dt) {
          const unsigned* vp = &Vt[p][(dt * 16 + l16) * 17 + quad * 4];
          V8u vf;
          vf.w[0] = vp[0]; vf.w[1] = vp[1]; vf.w[2] = vp[2]; vf.w[3] = vp[3];
          o[0][dt] = MFMA16(pf0, vf.v, o[0][dt]);
          o[1][dt] = MFMA16(pf1, vf.v, o[1][dt]);
        }
        o[0][8] = MFMA16(pf0, onesv, o[0][8]);
        o[1][8] = MFMA16(pf1, onesv, o[1][8]);
      }

      if (more) {
        *(short8*)&Ks[1 - p][(2 * sr2) * 136 + sc8]     = kr0;
        *(short8*)&Ks[1 - p][(2 * sr2 + 1) * 136 + sc8] = kr1;
        V8u a, c; a.v = vv0; c.v = vv1;
        #pragma unroll
        for (int j = 0; j < 8; ++j)
          Vt[1 - p][(sc8 + j) * 17 + sr2] = (unsigned)a.u[j] | ((unsigned)c.u[j] << 16);
      }
      __syncthreads();
    }

    // ---- epilogue: O / L -> ctx (merged-head layout [B*S][H]) ----
    #pragma unroll
    for (int g = 0; g < 2; ++g)
      #pragma unroll
      for (int r = 0; r < 4; ++r) {
        const float inv = 1.0f / o[g][8][r];
        const long qr = wqb + g * 16 + quad * 4 + r;
        #pragma unroll
        for (int dt = 0; dt < 8; ++dt)
          Cp[qr * HID + dt * 16 + l16] = f2bf(o[g][dt][r] * inv);
      }
  }
}

// ---------------------------------------------------------------------------
extern "C" void kernel_launch(void* const* d_in, const int* in_sizes, int n_in,
                              void* d_out, int out_size, void* d_ws, size_t ws_size,
                              hipStream_t stream) {
  const float* X  = (const float*)d_in[0];
  const float* wq = (const float*)d_in[1];
  const float* bq = (const float*)d_in[2];
  const float* wk = (const float*)d_in[3];
  const float* bk = (const float*)d_in[4];
  const float* wv = (const float*)d_in[5];
  const float* bv = (const float*)d_in[6];
  const float* wo = (const float*)d_in[7];
  const float* bo = (const float*)d_in[8];
  float* out = (float*)d_out;

  const long HSZ = 4096L * 2048;   // B*S x H
  const long WSZ = 2048L * 2048;
  // ws (bf16 elems): Qw Kw Vw (3x16.8MB) + Xb (16.8MB) + W0..W2 (3x8.4MB)
  u16* Qw = (u16*)d_ws;
  u16* Kw = Qw + HSZ;
  u16* Vw = Kw + HSZ;
  u16* Xb = Vw + HSZ;
  u16* Wb = Xb + HSZ;              // W0,W1,W2 contiguous after Xb
  u16* W0 = Wb;

  dim3 blk(256);
  // one fused conversion: X (2 segs) + wq + wk + wv into Xb..W2 (contiguous)
  conv5_f32_bf16<<<dim3((int)(WSZ / 2048), 5), blk, 0, stream>>>(X, wq, wk, wv, Xb, WSZ);

  // fused Q/K/V projections as ONE GEMM: M=4096, N=6144, K=2048.
  // grid 768 = exactly 3 blocks/CU (balanced; was 384 = 1.5 -> 25% idle).
  gemm_bal<false><<<dim3(768), dim3(512), 0, stream>>>(
      Xb, Wb, bq, bk, bv, Qw, 2048, 96);

  // causal flash attention (balanced heavy+light pairs); ctx in-place over Qw
  attn_fwd<<<dim3(8, 32), blk, 0, stream>>>(Qw, Kw, Vw, Qw);

  // output projection (fp32 out): grid 256 = exactly 1 block/CU.
  conv_f32_bf16<<<(int)(WSZ / 2048), blk, 0, stream>>>(wo, W0, WSZ);
  gemm_bal<true><<<dim3(256), dim3(512), 0, stream>>>(
      Qw, W0, bo, bo, bo, out, 2048, 32);
}

// Round 5
// 391.153 us; speedup vs baseline: 1.1523x; 1.0073x over previous
//
#include <hip/hip_runtime.h>
#include <stdint.h>

typedef unsigned short u16;
typedef __attribute__((ext_vector_type(8))) short short8;
typedef __attribute__((ext_vector_type(4))) short short4v;
typedef __attribute__((ext_vector_type(4))) float float4v;

union V8u { short8 v; short4v h[2]; u16 u[8]; unsigned w[4]; };

__device__ __forceinline__ u16 f2bf(float f) {
  unsigned u = __float_as_uint(f);
  u = u + 0x7FFFu + ((u >> 16) & 1u);   // round-to-nearest-even
  return (u16)(u >> 16);
}
__device__ __forceinline__ float4v fzero() {
  float4v z = {0.f, 0.f, 0.f, 0.f};
  return z;
}
__device__ __forceinline__ void gl_lds16(const u16* g, u16* l) {
  __builtin_amdgcn_global_load_lds(
      (const __attribute__((address_space(1))) void*)g,
      (__attribute__((address_space(3))) void*)l, 16, 0, 0);
}

#define MFMA16(a, b, c) __builtin_amdgcn_mfma_f32_16x16x32_bf16((a), (b), (c), 0, 0, 0)

// ---------------------------------------------------------------------------
// fp32 -> bf16 for 5 contiguous segments: X (2 segs) + wq,wk,wv. 8 elems/thr.
// ---------------------------------------------------------------------------
__global__ void conv5_f32_bf16(const float* __restrict__ X,
                               const float* __restrict__ w0,
                               const float* __restrict__ w1,
                               const float* __restrict__ w2,
                               u16* __restrict__ dst, long seg) {
  const int y = blockIdx.y;
  const float* s = (y < 2) ? (X + (long)y * seg)
                           : (y == 2 ? w0 : (y == 3 ? w1 : w2));
  u16* d = dst + (long)y * seg;
  const long i = ((long)blockIdx.x * 256 + threadIdx.x) * 8;
  if (i >= seg) return;
  float4 a = *(const float4*)&s[i];
  float4 b = *(const float4*)&s[i + 4];
  V8u o;
  o.u[0] = f2bf(a.x); o.u[1] = f2bf(a.y); o.u[2] = f2bf(a.z); o.u[3] = f2bf(a.w);
  o.u[4] = f2bf(b.x); o.u[5] = f2bf(b.y); o.u[6] = f2bf(b.z); o.u[7] = f2bf(b.w);
  *(short8*)&d[i] = o.v;
}

__global__ void conv_f32_bf16(const float* __restrict__ in, u16* __restrict__ out, long n) {
  const long i = ((long)blockIdx.x * 256 + threadIdx.x) * 8;
  if (i >= n) return;
  float4 a = *(const float4*)&in[i];
  float4 b = *(const float4*)&in[i + 4];
  V8u o;
  o.u[0] = f2bf(a.x); o.u[1] = f2bf(a.y); o.u[2] = f2bf(a.z); o.u[3] = f2bf(a.w);
  o.u[4] = f2bf(b.x); o.u[5] = f2bf(b.y); o.u[6] = f2bf(b.z); o.u[7] = f2bf(b.w);
  *(short8*)&out[i] = o.v;
}

// ---------------------------------------------------------------------------
// Balanced GEMM: O[m][n] = sum_k X[m][k]*W[n][k] + bias[n].
// BM=128, BN=256, BK=64, 512 thr / 8 waves (2M x 4N), per-wave 64x64.
//   QKV use:  M=4096, N=6144 -> grid 768 (3 balanced serial rounds, 1 blk/CU).
//   Out-proj: M=4096, N=2048 -> grid 256 = 1 block/CU exact.
// LDS: lds[3 bufs][A(128x64) | Blo(128x64) | Bup(128x64)] = 144 KiB.
//
// ONE barrier per K-tile: {stage kt+2 -> 16 ds_reads of kt -> 32 MFMA
// (setprio) -> vmcnt(6) -> s_barrier}. Reads and MFMA share the barrier
// window, so per-wave lgkmcnt gating + wave slip overlaps the LDS pipe with
// the MFMA pipe across the 2 waves/SIMD (R4's reads|BAR|MFMA structure
// serialized the pipes: measured 120.7us = LDS-read floor + MFMA floor).
// Hazards: stage in window kt+1 writes buf[kt%3], whose reads are all
// consumed (lgkm-drained) before the collective barrier ending window kt;
// vmcnt(6) at window end retires kt+1's 6 loads (issued one window back),
// keeps kt+2's 6 in flight -> queue never drains (T4).
// T2: byte ^= ((byte>>3)&0x70) swizzle, inverse-swizzled global source ->
//   0 bank conflicts (verified R1-R4).  T5: setprio around MFMA cluster.
// T1: bijective XCD swizzle; per-XCD chunk shares B-panels in its L2.
// ---------------------------------------------------------------------------
template <bool OUTF32>
__global__ __launch_bounds__(512, 2) void gemm_bal(
    const u16* __restrict__ X, const u16* __restrict__ Wb,
    const float* __restrict__ b0, const float* __restrict__ b1,
    const float* __restrict__ b2, void* __restrict__ Out,
    int K, int cpx)
{
  __shared__ __align__(16) u16 lds[3][3][8192];  // [buf][A|Blo|Bup][16 KiB]

  const int t = threadIdx.x;            // 0..511
  const int lane = t & 63;
  const int wave = t >> 6;              // 0..7
  const int quad = lane >> 4, l16 = lane & 15;
  const int wm = wave >> 2, wn = wave & 3;   // 2 x 4 wave grid

  // T1: XCD swizzle (grid % 8 == 0; cpx = grid/8). by fast -> A-col reuse,
  // bx chunked per XCD -> B-panel L2 reuse.
  const int bid = (int)blockIdx.x;
  const int swz = (bid & 7) * cpx + (bid >> 3);
  const int by = swz & 31;              // 32 M-tiles of 128
  const int bx = swz >> 5;              // N-tiles of 256
  const long m0 = (long)by * 128;
  const long n0 = (long)bx * 256;

  // --- staging precompute: dest d = l*8192 + t*16 (linear); logical
  //     o = d ^ ((d>>3)&0x70); row = o>>7 (l=0: 0..63, l=1: 64..127),
  //     col elem = (o&127)>>1.
  const u16* pA[2]; const u16* pBl[2]; const u16* pBu[2];
  #pragma unroll
  for (int l = 0; l < 2; ++l) {
    const int d = l * 8192 + t * 16;
    const int o = d ^ ((d >> 3) & 0x70);
    const int r = o >> 7;
    const int c = (o & 127) >> 1;
    pA[l]  = X  + (m0 + r) * (long)K + c;
    pBl[l] = Wb + (n0 + r) * (long)K + c;
    pBu[l] = Wb + (n0 + 128 + r) * (long)K + c;
  }

  // --- per-lane swizzled ds_read byte offsets (row base added separately) --
  int offk[2];
  #pragma unroll
  for (int kk = 0; kk < 2; ++kk)
    offk[kk] = l16 * 128 + ((kk * 64 + quad * 16) ^ ((l16 & 7) << 4));

  float4v acc[4][4];
  #pragma unroll
  for (int i = 0; i < 4; ++i)
    #pragma unroll
    for (int n = 0; n < 4; ++n) acc[i][n] = fzero();

#define STG(buf_, reg_, ptr_, kt_) do {                                        \
    gl_lds16(ptr_[0] + (long)(kt_) * 64, &lds[buf_][reg_][t * 8]);             \
    gl_lds16(ptr_[1] + (long)(kt_) * 64, &lds[buf_][reg_][4096 + t * 8]);      \
  } while (0)

#define BAR() do { asm volatile("s_barrier" ::: "memory");                     \
                   __builtin_amdgcn_sched_barrier(0); } while (0)

  const int NT = K >> 6;   // K-tiles of 64 (32 here)

  // --- prologue: kt0 -> buf0, kt1 -> buf1 (12 loads); wait kt0 resident ----
  STG(0, 0, pA, 0);  STG(0, 1, pBl, 0);  STG(0, 2, pBu, 0);
  STG(1, 0, pA, 1);  STG(1, 1, pBl, 1);  STG(1, 2, pBu, 1);
  asm volatile("s_waitcnt vmcnt(6)" ::: "memory");
  BAR();

  int buf = 0, sb = 2;   // current buffer, stage buffer (kt+2)%3
  for (int kt = 0; kt < NT; ++kt) {
    const int s2 = (kt + 2 < NT) ? kt + 2 : NT - 1;  // tail: dummy into dead buf
    const char* Ab = (const char*)&lds[buf][0][0] + wm * 8192;
    const char* Bb = (const char*)&lds[buf][1 + (wn >> 1)][0] + (wn & 1) * 8192;

    short8 a[4][2], b[4][2];

    // stage kt+2 (6 loads; retired by vmcnt(6) at END of window kt+1)
    STG(sb, 0, pA, s2);
    STG(sb, 1, pBl, s2);
    STG(sb, 2, pBu, s2);

    // reads + MFMA in ONE barrier window: per-wave lgkm gating lets this
    // wave's MFMAs overlap the SIMD-peer wave's ds_reads (setprio arbitrates)
    #pragma unroll
    for (int i = 0; i < 4; ++i)
      #pragma unroll
      for (int kk = 0; kk < 2; ++kk)
        a[i][kk] = *(const short8*)(Ab + i * 2048 + offk[kk]);
    #pragma unroll
    for (int n = 0; n < 4; ++n)
      #pragma unroll
      for (int kk = 0; kk < 2; ++kk)
        b[n][kk] = *(const short8*)(Bb + n * 2048 + offk[kk]);

    __builtin_amdgcn_s_setprio(1);
    #pragma unroll
    for (int i = 0; i < 4; ++i)
      #pragma unroll
      for (int n = 0; n < 4; ++n)
        #pragma unroll
        for (int kk = 0; kk < 2; ++kk)
          acc[i][n] = MFMA16(a[i][kk], b[n][kk], acc[i][n]);
    __builtin_amdgcn_s_setprio(0);

    asm volatile("s_waitcnt vmcnt(6)" ::: "memory");  // kt+1 fully resident
    BAR();

    buf = (buf == 2) ? 0 : buf + 1;
    sb  = (sb  == 2) ? 0 : sb  + 1;
  }
  asm volatile("s_waitcnt vmcnt(0)" ::: "memory");  // drain tail dummies

#undef STG
#undef BAR

  // --- epilogue: bias + store; segment z = col>>11 -------------------------
  #pragma unroll
  for (int n = 0; n < 4; ++n) {
    const int cg = (int)n0 + wn * 64 + n * 16 + l16;
    const int z = cg >> 11, col = cg & 2047;
    const float* Bp = (z == 0) ? b0 : (z == 1 ? b1 : b2);
    const float bvv = Bp[col];
    #pragma unroll
    for (int i = 0; i < 4; ++i) {
      const long r0 = m0 + wm * 64 + i * 16 + quad * 4;
      #pragma unroll
      for (int r = 0; r < 4; ++r) {
        const long off = (long)z * (4096L * 2048) + (r0 + r) * 2048 + col;
        const float v = acc[i][n][r] + bvv;
        if (OUTF32) ((float*)Out)[off] = v;
        else        ((u16*)Out)[off] = f2bf(v);
      }
    }
  }
}

// ---------------------------------------------------------------------------
// Causal flash attention, fixed-scale softmax + ones-column row-sum,
// 32 Q rows per wave / 128 Q rows per pass.
// BALANCED: grid.x = 8; block x sequentially processes Q-tile (15-x) [heavy]
// then Q-tile (x) [light] -> uniform 17 KV-tile-units per block. In-place
// Ctx-over-Qw stays safe: heavy passes write rows 1024..2047, light passes
// read rows 0..1023 (disjoint), and each block reads only its own rows /
// head-cols before writing them.
// ---------------------------------------------------------------------------
#define S_LEN 2048
#define HID   2048
#define HD    128

__global__ __launch_bounds__(256, 2) void attn_fwd(
    const u16* __restrict__ Q, const u16* __restrict__ K,
    const u16* __restrict__ V, u16* __restrict__ Ctx)
{
  __shared__ u16 Ks[2][32 * 136];      // K rows natural, pad 8
  __shared__ unsigned Vt[2][128 * 17]; // Vt[c][r/2] = V[2r'][c] | V[2r'+1][c]<<16
  __shared__ u16 Ps[4 * 2 * 512];      // per-wave, per-group P round-trip

  const int t = threadIdx.x;
  const int lane = t & 63, wave = t >> 6;
  const int quad = lane >> 4, l16 = lane & 15;
  const int b = blockIdx.y >> 4, h = blockIdx.y & 15;

  const long base = (long)b * S_LEN * HID + (long)h * HD;
  const u16* Qp = Q + base;
  const u16* Kp = K + base;
  const u16* Vp = V + base;
  u16* Cp = Ctx + base;

  const int sr2 = t >> 4;          // 0..15: rows 2*sr2, 2*sr2+1 of the tile
  const int sc8 = (t & 15) * 8;    // feature col base

  short8 onesv;
  {
    V8u ou;
    #pragma unroll
    for (int j = 0; j < 8; ++j) ou.u[j] = 0x3F80;   // bf16 1.0
    onesv = ou.v;
  }
  const float SC = 0.08838834764831845f * 1.4426950408889634f; // scale*log2e

  for (int pass = 0; pass < 2; ++pass) {
    const int qb = (pass ? (int)blockIdx.x : 15 - (int)blockIdx.x) * 128;
    const int wqb = qb + wave * 32;  // wave's first Q row

    // Q fragments for both groups (A-layout: m=lane&15, k=quad*8+j)
    short8 qf[2][4];
    #pragma unroll
    for (int g = 0; g < 2; ++g) {
      const long qr = wqb + g * 16 + l16;
      #pragma unroll
      for (int kk = 0; kk < 4; ++kk)
        qf[g][kk] = *(const short8*)&Qp[qr * HID + kk * 32 + quad * 8];
    }

    float4v o[2][9];                 // per group: [0..7] d-groups, [8] row-sum
    #pragma unroll
    for (int g = 0; g < 2; ++g)
      #pragma unroll
      for (int i = 0; i < 9; ++i) o[g][i] = fzero();

    // prefetch tile 0 into regs, commit to buf 0
    short8 kr0, kr1, vv0, vv1;
    {
      const long g = (long)(2 * sr2) * HID + sc8;
      kr0 = *(const short8*)&Kp[g];
      kr1 = *(const short8*)&Kp[g + HID];
      vv0 = *(const short8*)&Vp[g];
      vv1 = *(const short8*)&Vp[g + HID];
    }
    {
      *(short8*)&Ks[0][(2 * sr2) * 136 + sc8]     = kr0;
      *(short8*)&Ks[0][(2 * sr2 + 1) * 136 + sc8] = kr1;
      V8u a, c; a.v = vv0; c.v = vv1;
      #pragma unroll
      for (int j = 0; j < 8; ++j)
        Vt[0][(sc8 + j) * 17 + sr2] = (unsigned)a.u[j] | ((unsigned)c.u[j] << 16);
    }
    __syncthreads();

    const int T = (qb + 128) >> 5;   // number of 32-row KV tiles
    for (int ti = 0; ti < T; ++ti) {
      const int kv0 = ti << 5;
      const int p = ti & 1;

      const bool more = (ti + 1 < T);
      if (more) {
        const long g = (long)(kv0 + 32 + 2 * sr2) * HID + sc8;
        kr0 = *(const short8*)&Kp[g];
        kr1 = *(const short8*)&Kp[g + HID];
        vv0 = *(const short8*)&Vp[g];
        vv1 = *(const short8*)&Vp[g + HID];
      }

      // wave-uniform activity: both groups share it (kv0, wqb 32-aligned)
      if (kv0 <= wqb) {
        // ---- S = Q . K^T for both groups (kf read once, used twice) ----
        float4v s[2][2];
        #pragma unroll
        for (int g = 0; g < 2; ++g) { s[g][0] = fzero(); s[g][1] = fzero(); }
        #pragma unroll
        for (int ni = 0; ni < 2; ++ni)
          #pragma unroll
          for (int kk = 0; kk < 4; ++kk) {
            short8 kf = *(const short8*)&Ks[p][(ni * 16 + l16) * 136 + kk * 32 + quad * 8];
            s[0][ni] = MFMA16(qf[0][kk], kf, s[0][ni]);
            s[1][ni] = MFMA16(qf[1][kk], kf, s[1][ni]);
          }

        // ---- fixed-scale exp + causal mask + P round-trip per group ----
        const int pb = wave * 1024;
        #pragma unroll
        for (int g = 0; g < 2; ++g) {
          const int qrow0 = wqb + g * 16 + quad * 4;
          #pragma unroll
          for (int r = 0; r < 4; ++r) {
            float s0 = fminf(s[g][0][r] * SC, 80.f);
            float s1 = fminf(s[g][1][r] * SC, 80.f);
            if (kv0 + l16 > qrow0 + r)      s0 = -1e30f;
            if (kv0 + 16 + l16 > qrow0 + r) s1 = -1e30f;
            Ps[pb + g * 512 + (quad * 4 + r) * 32 + l16]      = f2bf(__builtin_amdgcn_exp2f(s0));
            Ps[pb + g * 512 + (quad * 4 + r) * 32 + 16 + l16] = f2bf(__builtin_amdgcn_exp2f(s1));
          }
        }
        __threadfence_block();
        short8 pf0 = *(const short8*)&Ps[pb + l16 * 32 + quad * 8];
        short8 pf1 = *(const short8*)&Ps[pb + 512 + l16 * 32 + quad * 8];

        // ---- O += P . V (vf read once, used twice) ; ones row-sum ----
        #pragma unroll
        for (int dt = 0; dt < 8; ++dt) {
          const unsigned* vp = &Vt[p][(dt * 16 + l16) * 17 + quad * 4];
          V8u vf;
          vf.w[0] = vp[0]; vf.w[1] = vp[1]; vf.w[2] = vp[2]; vf.w[3] = vp[3];
          o[0][dt] = MFMA16(pf0, vf.v, o[0][dt]);
          o[1][dt] = MFMA16(pf1, vf.v, o[1][dt]);
        }
        o[0][8] = MFMA16(pf0, onesv, o[0][8]);
        o[1][8] = MFMA16(pf1, onesv, o[1][8]);
      }

      if (more) {
        *(short8*)&Ks[1 - p][(2 * sr2) * 136 + sc8]     = kr0;
        *(short8*)&Ks[1 - p][(2 * sr2 + 1) * 136 + sc8] = kr1;
        V8u a, c; a.v = vv0; c.v = vv1;
        #pragma unroll
        for (int j = 0; j < 8; ++j)
          Vt[1 - p][(sc8 + j) * 17 + sr2] = (unsigned)a.u[j] | ((unsigned)c.u[j] << 16);
      }
      __syncthreads();
    }

    // ---- epilogue: O / L -> ctx (merged-head layout [B*S][H]) ----
    #pragma unroll
    for (int g = 0; g < 2; ++g)
      #pragma unroll
      for (int r = 0; r < 4; ++r) {
        const float inv = 1.0f / o[g][8][r];
        const long qr = wqb + g * 16 + quad * 4 + r;
        #pragma unroll
        for (int dt = 0; dt < 8; ++dt)
          Cp[qr * HID + dt * 16 + l16] = f2bf(o[g][dt][r] * inv);
      }
  }
}

// ---------------------------------------------------------------------------
extern "C" void kernel_launch(void* const* d_in, const int* in_sizes, int n_in,
                              void* d_out, int out_size, void* d_ws, size_t ws_size,
                              hipStream_t stream) {
  const float* X  = (const float*)d_in[0];
  const float* wq = (const float*)d_in[1];
  const float* bq = (const float*)d_in[2];
  const float* wk = (const float*)d_in[3];
  const float* bk = (const float*)d_in[4];
  const float* wv = (const float*)d_in[5];
  const float* bv = (const float*)d_in[6];
  const float* wo = (const float*)d_in[7];
  const float* bo = (const float*)d_in[8];
  float* out = (float*)d_out;

  const long HSZ = 4096L * 2048;   // B*S x H
  const long WSZ = 2048L * 2048;
  // ws (bf16 elems): Qw Kw Vw (3x16.8MB) + Xb (16.8MB) + W0..W2 (3x8.4MB)
  u16* Qw = (u16*)d_ws;
  u16* Kw = Qw + HSZ;
  u16* Vw = Kw + HSZ;
  u16* Xb = Vw + HSZ;
  u16* Wb = Xb + HSZ;              // W0,W1,W2 contiguous after Xb
  u16* W0 = Wb;

  dim3 blk(256);
  // one fused conversion: X (2 segs) + wq + wk + wv into Xb..W2 (contiguous)
  conv5_f32_bf16<<<dim3((int)(WSZ / 2048), 5), blk, 0, stream>>>(X, wq, wk, wv, Xb, WSZ);

  // fused Q/K/V projections as ONE GEMM: M=4096, N=6144, K=2048.
  gemm_bal<false><<<dim3(768), dim3(512), 0, stream>>>(
      Xb, Wb, bq, bk, bv, Qw, 2048, 96);

  // causal flash attention (balanced heavy+light pairs); ctx in-place over Qw
  attn_fwd<<<dim3(8, 32), blk, 0, stream>>>(Qw, Kw, Vw, Qw);

  // output projection (fp32 out): grid 256 = exactly 1 block/CU.
  conv_f32_bf16<<<(int)(WSZ / 2048), blk, 0, stream>>>(wo, W0, WSZ);
  gemm_bal<true><<<dim3(256), dim3(512), 0, stream>>>(
      Qw, W0, bo, bo, bo, out, 2048, 32);
}